// Round 1
// baseline (1386.037 us; speedup 1.0000x reference)
//
#include <hip/hip_runtime.h>
#include <hip/hip_bf16.h>
#include <stdint.h>

#define DD 128

typedef short bf16x8 __attribute__((ext_vector_type(8)));
typedef float f32x4 __attribute__((ext_vector_type(4)));

__device__ __forceinline__ short f2bf(float f){
  union { float f; uint32_t u; } v; v.f = f;
  uint32_t r = v.u + 0x7fffu + ((v.u >> 16) & 1u);
  return (short)(r >> 16);
}
__device__ __forceinline__ float bf2f(short s){
  union { uint32_t u; float f; } v; v.u = ((uint32_t)(uint16_t)s) << 16;
  return v.f;
}
__device__ __forceinline__ float sigm(float x){ return 1.0f/(1.0f + __expf(-x)); }
__device__ __forceinline__ float tanh_f(float x){ return 1.0f - 2.0f/(__expf(2.0f*x) + 1.0f); }

// ---------------- small prep kernels ----------------

__global__ void zero_stats_k(float* sum, float* sumsq, int* flag){
  int t = threadIdx.x;
  if(t < DD){ sum[t] = 0.f; sumsq[t] = 0.f; }
  if(t == 0) *flag = 0;
}

__global__ void init_deg_k(int* deg, int n){
  int i = blockIdx.x*256 + threadIdx.x;
  if(i < n) deg[i] = 1;  // self loop
}

// Detect edge_index storage: if the buffer is int64, every odd int32 word is a
// zero high-word (indices < 2^31). If int32, odd words are random node ids.
__global__ void flag_k(const int* e32, int* flag, int e){
  int i = blockIdx.x*256 + threadIdx.x;
  if(i < e && e32[2*i+1] != 0) *flag = 1;   // benign race: all write 1
}

__device__ __forceinline__ int eidx(const int* e32, int is32, long pos, int n){
  int v = is32 ? e32[pos] : e32[2*pos];
  return v < 0 ? 0 : (v >= n ? n-1 : v);
}

__global__ void deg_k(const int* e32, const int* flag, int* deg, int e, int n){
  int i = blockIdx.x*256 + threadIdx.x;
  if(i >= e) return;
  int is32 = *flag;
  int c = eidx(e32, is32, (long)e + i, n);  // cols = targets
  atomicAdd(&deg[c], 1);
}

__global__ void dinv_k(const int* deg, float* dinv, int n){
  int i = blockIdx.x*256 + threadIdx.x;
  if(i < n) dinv[i] = rsqrtf((float)deg[i]);
}

// Wt[n*K + k] = bf16(W[k*Nout + n])   (transpose + convert)
__global__ void cvtw_k(const float* w, short* wt, int K, int Nout){
  int t = blockIdx.x*256 + threadIdx.x;
  if(t >= K*Nout) return;
  int nn = t / K, k = t - nn*K;
  wt[t] = f2bf(w[k*Nout + nn]);
}

// agg[i] = x[i] * dinv[i]^2   (self-loop term, also initializes agg)
__global__ void selfloop_k(const float* x, const float* dinv, float* agg, int n){
  int t = blockIdx.x*256 + threadIdx.x;
  if(t >= n*32) return;
  int i = t >> 5, d4 = t & 31;
  float s = dinv[i]*dinv[i];
  f32x4 v = *(const f32x4*)(x + (long)i*DD + d4*4);
  *(f32x4*)(agg + (long)i*DD + d4*4) = v*s;
}

__global__ void scatter_k(const float* x, const float* dinv, const int* e32,
                          const int* flag, float* agg, int e, int n){
  long t = (long)blockIdx.x*256 + threadIdx.x;
  if(t >= (long)e*32) return;
  int ei = (int)(t >> 5), d4 = (int)(t & 31);
  int is32 = *flag;
  int r = eidx(e32, is32, ei, n);
  int c = eidx(e32, is32, (long)e + ei, n);
  float nrm = dinv[r]*dinv[c];
  f32x4 v = *(const f32x4*)(x + (long)r*DD + d4*4);
  float* dst = agg + (long)c*DD + d4*4;
  atomicAdd(dst+0, v[0]*nrm);
  atomicAdd(dst+1, v[1]*nrm);
  atomicAdd(dst+2, v[2]*nrm);
  atomicAdd(dst+3, v[3]*nrm);
}

// ---------------- GEMM 1: h_raw = agg @ W_gcn + b_gcn  (store bf16) ----------------
// block: 256 thr (4 waves), M-tile 64, N=128, K=128. Wave w owns n-tiles {2w, 2w+1}.

__global__ __launch_bounds__(256) void gemm_h_k(const float* agg, const short* wt,
    const float* bias, short* hraw, int n){
  __shared__ char Alds[64*256];  // 64 rows x 128 bf16, XOR-swizzled
  const int t = threadIdx.x;
  const int row0 = blockIdx.x*64;
  for(int u = t; u < 1024; u += 256){
    int r = u >> 4, ku = u & 15;
    int grow = row0 + r;
    f32x4 a = {0,0,0,0}, b = {0,0,0,0};
    if(grow < n){
      const f32x4* p = (const f32x4*)(agg + (long)grow*DD + ku*8);
      a = p[0]; b = p[1];
    }
    bf16x8 wv;
    #pragma unroll
    for(int j = 0; j < 4; j++){ wv[j] = f2bf(a[j]); wv[4+j] = f2bf(b[j]); }
    int byte = r*256 + ((ku*16) ^ ((r&7)<<4));
    *(bf16x8*)(Alds + byte) = wv;
  }
  __syncthreads();
  const int w = t >> 6, l = t & 63;
  const int lrow = l & 15, lk = l >> 4;
  f32x4 acc[4][2];
  #pragma unroll
  for(int m = 0; m < 4; m++) for(int j = 0; j < 2; j++) acc[m][j] = (f32x4){0,0,0,0};
  #pragma unroll
  for(int ks = 0; ks < 4; ks++){
    bf16x8 af[4];
    #pragma unroll
    for(int m = 0; m < 4; m++){
      int r = m*16 + lrow;
      int byte = r*256 + ((ks*64 + lk*16) ^ ((r&7)<<4));
      af[m] = *(const bf16x8*)(Alds + byte);
    }
    #pragma unroll
    for(int j = 0; j < 2; j++){
      int col = (w*2+j)*16 + lrow;
      bf16x8 bfr = *(const bf16x8*)(wt + col*128 + ks*32 + lk*8);
      #pragma unroll
      for(int m = 0; m < 4; m++)
        acc[m][j] = __builtin_amdgcn_mfma_f32_16x16x32_bf16(af[m], bfr, acc[m][j], 0,0,0);
    }
  }
  #pragma unroll
  for(int j = 0; j < 2; j++){
    int col = (w*2+j)*16 + lrow;
    float bv = bias[col];
    #pragma unroll
    for(int m = 0; m < 4; m++){
      int rb = row0 + m*16 + lk*4;
      #pragma unroll
      for(int rr = 0; rr < 4; rr++){
        int row = rb + rr;
        if(row < n) hraw[(long)row*DD + col] = f2bf(acc[m][j][rr] + bv);
      }
    }
  }
}

// ---------------- BN stats over h_raw ----------------

__global__ __launch_bounds__(256) void stats_k(const short* hraw, float* sum,
                                               float* sumsq, int n){
  __shared__ float ls[256], ls2[256];
  int t = threadIdx.x;
  int col = t & 127, half = t >> 7;
  int rpb = (n + gridDim.x - 1) / gridDim.x;
  int r0 = blockIdx.x*rpb;
  int r1 = r0 + rpb; if(r1 > n) r1 = n;
  float s = 0.f, s2 = 0.f;
  for(int r = r0 + half; r < r1; r += 2){
    float v = bf2f(hraw[(long)r*DD + col]);
    s += v; s2 += v*v;
  }
  ls[t] = s; ls2[t] = s2;
  __syncthreads();
  if(t < 128){
    s = ls[t] + ls[t+128]; s2 = ls2[t] + ls2[t+128];
    atomicAdd(&sum[col], s); atomicAdd(&sumsq[col], s2);
  }
}

__global__ void bnfin_k(const float* sum, const float* sumsq, const float* gamma,
                        const float* beta, float* scale, float* shift, int n){
  int c = threadIdx.x;
  if(c >= DD) return;
  float inv_n = 1.0f/(float)n;
  float mean = sum[c]*inv_n;
  float var = sumsq[c]*inv_n - mean*mean;
  float sc = gamma[c]*rsqrtf(var + 1e-5f);
  scale[c] = sc;
  shift[c] = beta[c] - mean*sc;
}

// ---------------- GEMM 2: [h_act | H] @ [Wz|Wr] -> Z (bf16), RH = sigmoid(.)*H (bf16) ----
// block: 256 thr, M-tile 64, Nout=256, K=256. Wave w owns n-tiles {4w..4w+3}.

__global__ __launch_bounds__(256) void gemm_zr_k(const short* hraw, const float* H,
    const short* wtzr, const float* scale, const float* shift, const float* prelu,
    const float* bz, const float* br, short* Z, short* RH, int n){
  __shared__ char Alds[64*512];  // 64 rows x 256 bf16, swizzled
  const int t = threadIdx.x;
  const int row0 = blockIdx.x*64;
  const float pa = prelu[0];
  for(int u = t; u < 2048; u += 256){
    int r = u >> 5, ku = u & 31;
    int grow = row0 + r;
    bf16x8 wv = {0,0,0,0,0,0,0,0};
    if(ku < 16){
      if(grow < n){
        bf16x8 hv = *(const bf16x8*)(hraw + (long)grow*DD + ku*8);
        #pragma unroll
        for(int j = 0; j < 8; j++){
          int c = ku*8 + j;
          float f = bf2f(hv[j])*scale[c] + shift[c];
          f = f > 0.f ? f : pa*f;
          wv[j] = f2bf(f);
        }
      }
    } else {
      if(grow < n){
        const f32x4* p = (const f32x4*)(H + (long)grow*DD + (ku-16)*8);
        f32x4 a = p[0], b = p[1];
        #pragma unroll
        for(int j = 0; j < 4; j++){ wv[j] = f2bf(a[j]); wv[4+j] = f2bf(b[j]); }
      }
    }
    int byte = r*512 + ((ku*16) ^ ((r&7)<<4));
    *(bf16x8*)(Alds + byte) = wv;
  }
  __syncthreads();
  const int w = t >> 6, l = t & 63;
  const int lrow = l & 15, lk = l >> 4;
  f32x4 acc[4][4];
  #pragma unroll
  for(int m = 0; m < 4; m++) for(int j = 0; j < 4; j++) acc[m][j] = (f32x4){0,0,0,0};
  #pragma unroll
  for(int ks = 0; ks < 8; ks++){
    bf16x8 af[4];
    #pragma unroll
    for(int m = 0; m < 4; m++){
      int r = m*16 + lrow;
      int byte = r*512 + ((ks*64 + lk*16) ^ ((r&7)<<4));
      af[m] = *(const bf16x8*)(Alds + byte);
    }
    #pragma unroll
    for(int j = 0; j < 4; j++){
      int col = (w*4+j)*16 + lrow;
      bf16x8 bfr = *(const bf16x8*)(wtzr + (long)col*256 + ks*32 + lk*8);
      #pragma unroll
      for(int m = 0; m < 4; m++)
        acc[m][j] = __builtin_amdgcn_mfma_f32_16x16x32_bf16(af[m], bfr, acc[m][j], 0,0,0);
    }
  }
  #pragma unroll
  for(int j = 0; j < 4; j++){
    int col256 = (w*4+j)*16 + lrow;
    if(col256 < 128){
      float bv = bz[col256];
      #pragma unroll
      for(int m = 0; m < 4; m++){
        #pragma unroll
        for(int rr = 0; rr < 4; rr++){
          int row = row0 + m*16 + lk*4 + rr;
          if(row < n) Z[(long)row*DD + col256] = f2bf(sigm(acc[m][j][rr] + bv));
        }
      }
    } else {
      int col = col256 - 128;
      float bv = br[col];
      #pragma unroll
      for(int m = 0; m < 4; m++){
        #pragma unroll
        for(int rr = 0; rr < 4; rr++){
          int row = row0 + m*16 + lk*4 + rr;
          if(row < n){
            float rv = sigm(acc[m][j][rr] + bv);
            float hv = H[(long)row*DD + col];
            RH[(long)row*DD + col] = f2bf(rv*hv);
          }
        }
      }
    }
  }
}

// ---------------- GEMM 3: [h_act | RH] @ Wh -> H_tilde; out = Z*H + (1-Z)*tanh ---------

__global__ __launch_bounds__(256) void gemm_ht_k(const short* hraw, const short* RH,
    const short* wth, const float* scale, const float* shift, const float* prelu,
    const float* bh, const short* Z, const float* H, float* out, int n){
  __shared__ char Alds[64*512];
  const int t = threadIdx.x;
  const int row0 = blockIdx.x*64;
  const float pa = prelu[0];
  for(int u = t; u < 2048; u += 256){
    int r = u >> 5, ku = u & 31;
    int grow = row0 + r;
    bf16x8 wv = {0,0,0,0,0,0,0,0};
    if(ku < 16){
      if(grow < n){
        bf16x8 hv = *(const bf16x8*)(hraw + (long)grow*DD + ku*8);
        #pragma unroll
        for(int j = 0; j < 8; j++){
          int c = ku*8 + j;
          float f = bf2f(hv[j])*scale[c] + shift[c];
          f = f > 0.f ? f : pa*f;
          wv[j] = f2bf(f);
        }
      }
    } else {
      if(grow < n) wv = *(const bf16x8*)(RH + (long)grow*DD + (ku-16)*8);
    }
    int byte = r*512 + ((ku*16) ^ ((r&7)<<4));
    *(bf16x8*)(Alds + byte) = wv;
  }
  __syncthreads();
  const int w = t >> 6, l = t & 63;
  const int lrow = l & 15, lk = l >> 4;
  f32x4 acc[4][2];
  #pragma unroll
  for(int m = 0; m < 4; m++) for(int j = 0; j < 2; j++) acc[m][j] = (f32x4){0,0,0,0};
  #pragma unroll
  for(int ks = 0; ks < 8; ks++){
    bf16x8 af[4];
    #pragma unroll
    for(int m = 0; m < 4; m++){
      int r = m*16 + lrow;
      int byte = r*512 + ((ks*64 + lk*16) ^ ((r&7)<<4));
      af[m] = *(const bf16x8*)(Alds + byte);
    }
    #pragma unroll
    for(int j = 0; j < 2; j++){
      int col = (w*2+j)*16 + lrow;
      bf16x8 bfr = *(const bf16x8*)(wth + (long)col*256 + ks*32 + lk*8);
      #pragma unroll
      for(int m = 0; m < 4; m++)
        acc[m][j] = __builtin_amdgcn_mfma_f32_16x16x32_bf16(af[m], bfr, acc[m][j], 0,0,0);
    }
  }
  #pragma unroll
  for(int j = 0; j < 2; j++){
    int col = (w*2+j)*16 + lrow;
    float bv = bh[col];
    #pragma unroll
    for(int m = 0; m < 4; m++){
      #pragma unroll
      for(int rr = 0; rr < 4; rr++){
        int row = row0 + m*16 + lk*4 + rr;
        if(row < n){
          float ht = tanh_f(acc[m][j][rr] + bv);
          float z = bf2f(Z[(long)row*DD + col]);
          float Hv = H[(long)row*DD + col];
          out[(long)row*DD + col] = z*Hv + (1.f - z)*ht;
        }
      }
    }
  }
}

// ---------------- launch ----------------

extern "C" void kernel_launch(void* const* d_in, const int* in_sizes, int n_in,
                              void* d_out, int out_size, void* d_ws, size_t ws_size,
                              hipStream_t stream){
  const float* x     = (const float*)d_in[0];
  const int*   e32   = (const int*)d_in[1];
  const float* H     = (const float*)d_in[2];
  const float* Wg    = (const float*)d_in[3];
  const float* bg    = (const float*)d_in[4];
  const float* gamma = (const float*)d_in[5];
  const float* beta  = (const float*)d_in[6];
  const float* prelu = (const float*)d_in[7];
  const float* Wz    = (const float*)d_in[8];
  const float* bz    = (const float*)d_in[9];
  const float* Wr    = (const float*)d_in[10];
  const float* br    = (const float*)d_in[11];
  const float* Wh    = (const float*)d_in[12];
  const float* bh    = (const float*)d_in[13];
  float* out = (float*)d_out;
  const int n = in_sizes[0] / DD;
  const int e = in_sizes[1] / 2;

  char* ws = (char*)d_ws;
  size_t o = 0;
  auto alloc = [&](size_t bytes)->char*{
    char* p = ws + o; o = (o + bytes + 255) & ~(size_t)255; return p;
  };
  int*   deg   = (int*)  alloc(4L*n);
  float* dinv  = (float*)alloc(4L*n);
  int*   flag  = (int*)  alloc(256);
  float* sum   = (float*)alloc(512);
  float* sumsq = (float*)alloc(512);
  float* scale = (float*)alloc(512);
  float* shift = (float*)alloc(512);
  short* wtg   = (short*)alloc(128L*128*2);
  short* wtzr  = (short*)alloc(256L*256*2);
  short* wth   = (short*)alloc(128L*256*2);
  float* agg   = (float*)alloc(4L*n*DD);
  short* hraw  = (short*)alloc(2L*n*DD);
  short* Zb    = (short*)alloc(2L*n*DD);
  short* RHb   = (short*)alloc(2L*n*DD);

  zero_stats_k<<<1, 256, 0, stream>>>(sum, sumsq, flag);
  init_deg_k<<<(n+255)/256, 256, 0, stream>>>(deg, n);
  flag_k<<<(e+255)/256, 256, 0, stream>>>(e32, flag, e);
  deg_k<<<(e+255)/256, 256, 0, stream>>>(e32, flag, deg, e, n);
  dinv_k<<<(n+255)/256, 256, 0, stream>>>(deg, dinv, n);
  cvtw_k<<<(128*128+255)/256, 256, 0, stream>>>(Wg, wtg, 128, 128);
  cvtw_k<<<(256*128+255)/256, 256, 0, stream>>>(Wz, wtzr, 256, 128);
  cvtw_k<<<(256*128+255)/256, 256, 0, stream>>>(Wr, wtzr + 128*256, 256, 128);
  cvtw_k<<<(256*128+255)/256, 256, 0, stream>>>(Wh, wth, 256, 128);
  selfloop_k<<<(n*32+255)/256, 256, 0, stream>>>(x, dinv, agg, n);
  scatter_k<<<(int)(((long)e*32 + 255)/256), 256, 0, stream>>>(x, dinv, e32, flag, agg, e, n);
  const int gb = (n + 63)/64;
  gemm_h_k<<<gb, 256, 0, stream>>>(agg, wtg, bg, hraw, n);
  stats_k<<<1024, 256, 0, stream>>>(hraw, sum, sumsq, n);
  bnfin_k<<<1, 128, 0, stream>>>(sum, sumsq, gamma, beta, scale, shift, n);
  gemm_zr_k<<<gb, 256, 0, stream>>>(hraw, H, wtzr, scale, shift, prelu, bz, br, Zb, RHb, n);
  gemm_ht_k<<<gb, 256, 0, stream>>>(hraw, RHb, wth, scale, shift, prelu, bh, Zb, H, out, n);
}

// Round 2
// 392.389 us; speedup vs baseline: 3.5323x; 3.5323x over previous
//
#include <hip/hip_runtime.h>
#include <hip/hip_bf16.h>
#include <stdint.h>

#define DD 128
#define CHUNK 1024

typedef short bf16x8 __attribute__((ext_vector_type(8)));
typedef short bf16x4 __attribute__((ext_vector_type(4)));
typedef float f32x4 __attribute__((ext_vector_type(4)));

__device__ __forceinline__ short f2bf(float f){
  union { float f; uint32_t u; } v; v.f = f;
  uint32_t r = v.u + 0x7fffu + ((v.u >> 16) & 1u);
  return (short)(r >> 16);
}
__device__ __forceinline__ float bf2f(short s){
  union { uint32_t u; float f; } v; v.u = ((uint32_t)(uint16_t)s) << 16;
  return v.f;
}
__device__ __forceinline__ float sigm(float x){ return 1.0f/(1.0f + __expf(-x)); }
__device__ __forceinline__ float tanh_f(float x){ return 1.0f - 2.0f/(__expf(2.0f*x) + 1.0f); }

// ---------------- small prep kernels ----------------

__global__ void zero_stats_k(float* sum, float* sumsq, int* flag){
  int t = threadIdx.x;
  if(t < DD){ sum[t] = 0.f; sumsq[t] = 0.f; }
  if(t == 0) *flag = 0;
}

__global__ void init_deg_k(int* deg, int n){
  int i = blockIdx.x*256 + threadIdx.x;
  if(i < n) deg[i] = 1;  // self loop
}

// Detect edge_index storage: int64 buffers have zero odd int32 words.
__global__ void flag_k(const int* e32, int* flag, int e){
  int i = blockIdx.x*256 + threadIdx.x;
  if(i < e && e32[2*i+1] != 0) *flag = 1;   // benign race: all write 1
}

__device__ __forceinline__ int eidx(const int* e32, int is32, long pos, int n){
  int v = is32 ? e32[pos] : e32[2*pos];
  return v < 0 ? 0 : (v >= n ? n-1 : v);
}

__global__ void deg_k(const int* e32, const int* flag, int* deg, int e, int n){
  int i = blockIdx.x*256 + threadIdx.x;
  if(i >= e) return;
  int is32 = *flag;
  int c = eidx(e32, is32, (long)e + i, n);  // cols = targets
  atomicAdd(&deg[c], 1);
}

__global__ void dinv_k(const int* deg, float* dinv, int n){
  int i = blockIdx.x*256 + threadIdx.x;
  if(i < n) dinv[i] = rsqrtf((float)deg[i]);
}

// Wt[n*K + k] = bf16(W[k*Nout + n])   (transpose + convert)
__global__ void cvtw_k(const float* w, short* wt, int K, int Nout){
  int t = blockIdx.x*256 + threadIdx.x;
  if(t >= K*Nout) return;
  int nn = t / K, k = t - nn*K;
  wt[t] = f2bf(w[k*Nout + nn]);
}

// ---------------- CSR build: exclusive scan of (deg-1), bucket fill ----------------

__global__ __launch_bounds__(256) void scanA_k(const int* deg, int* bsum, int n){
  __shared__ int ls[256];
  int b = blockIdx.x, t = threadIdx.x;
  int base = b*CHUNK + t*4;
  int s = 0;
  #pragma unroll
  for(int j = 0; j < 4; j++){ int i = base + j; if(i < n) s += deg[i] - 1; }
  ls[t] = s; __syncthreads();
  for(int off = 128; off > 0; off >>= 1){
    if(t < off) ls[t] += ls[t+off];
    __syncthreads();
  }
  if(t == 0) bsum[b] = ls[0];
}

__global__ void scanB_k(int* bsum, int nb){
  if(threadIdx.x == 0){
    int acc = 0;
    for(int i = 0; i < nb; i++){ int v = bsum[i]; bsum[i] = acc; acc += v; }
  }
}

__global__ __launch_bounds__(256) void scanC_k(const int* deg, const int* bsum,
                                               int* off, int* cursor, int n){
  __shared__ int ls[256];
  int b = blockIdx.x, t = threadIdx.x;
  int base = b*CHUNK + t*4;
  int v[4]; int s = 0;
  #pragma unroll
  for(int j = 0; j < 4; j++){ int i = base + j; v[j] = (i < n) ? deg[i]-1 : 0; s += v[j]; }
  ls[t] = s; __syncthreads();
  for(int d = 1; d < 256; d <<= 1){
    int tmp = (t >= d) ? ls[t-d] : 0;
    __syncthreads();
    ls[t] += tmp;
    __syncthreads();
  }
  int run = bsum[b] + ls[t] - s;   // exclusive prefix
  #pragma unroll
  for(int j = 0; j < 4; j++){
    int i = base + j;
    if(i < n){ off[i] = run; cursor[i] = run; run += v[j]; }
  }
}

__global__ void fill_k(const int* e32, const int* flag, int* cursor, int* srcs,
                       int e, int n){
  int i = blockIdx.x*256 + threadIdx.x;
  if(i >= e) return;
  int is32 = *flag;
  int r = eidx(e32, is32, i, n);
  int c = eidx(e32, is32, (long)e + i, n);
  int slot = atomicAdd(&cursor[c], 1);
  srcs[slot] = r;
}

// ---------------- CSR gather: agg[i] = dinv[i]^2*x[i] + sum_r dinv[i]dinv[r]*x[r] ----
// One 32-lane group per node; lane d4 owns floats [4*d4, 4*d4+4). Output bf16.

__global__ __launch_bounds__(256) void gather_k(const float* x, const float* dinv,
    const int* off, const int* deg, const int* srcs, short* aggb, int n){
  int t = threadIdx.x;
  int g = blockIdx.x*8 + (t >> 5);
  int d4 = t & 31;
  if(g >= n) return;
  float di = dinv[g];
  f32x4 acc = *(const f32x4*)(x + (long)g*DD + d4*4);
  acc *= di*di;
  int o0 = off[g], cnt = deg[g] - 1;
  for(int j = 0; j < cnt; j++){
    int r = srcs[o0 + j];
    float nrm = di*dinv[r];
    f32x4 v = *(const f32x4*)(x + (long)r*DD + d4*4);
    acc += v*nrm;
  }
  bf16x4 o;
  #pragma unroll
  for(int j = 0; j < 4; j++) o[j] = f2bf(acc[j]);
  *(bf16x4*)(aggb + (long)g*DD + d4*4) = o;
}

// ---------------- GEMM 1: h_raw = aggb @ W_gcn + b_gcn  (bf16 in, bf16 out) ----------
// block: 256 thr (4 waves), M-tile 64, N=128, K=128. Wave w owns n-tiles {2w, 2w+1}.

__global__ __launch_bounds__(256) void gemm_h_k(const short* aggb, const short* wt,
    const float* bias, short* hraw, int n){
  __shared__ char Alds[64*256];  // 64 rows x 128 bf16, XOR-swizzled
  const int t = threadIdx.x;
  const int row0 = blockIdx.x*64;
  for(int u = t; u < 1024; u += 256){
    int r = u >> 4, ku = u & 15;
    int grow = row0 + r;
    bf16x8 wv = {0,0,0,0,0,0,0,0};
    if(grow < n) wv = *(const bf16x8*)(aggb + (long)grow*DD + ku*8);
    int byte = r*256 + ((ku*16) ^ ((r&7)<<4));
    *(bf16x8*)(Alds + byte) = wv;
  }
  __syncthreads();
  const int w = t >> 6, l = t & 63;
  const int lrow = l & 15, lk = l >> 4;
  f32x4 acc[4][2];
  #pragma unroll
  for(int m = 0; m < 4; m++) for(int j = 0; j < 2; j++) acc[m][j] = (f32x4){0,0,0,0};
  #pragma unroll
  for(int ks = 0; ks < 4; ks++){
    bf16x8 af[4];
    #pragma unroll
    for(int m = 0; m < 4; m++){
      int r = m*16 + lrow;
      int byte = r*256 + ((ks*64 + lk*16) ^ ((r&7)<<4));
      af[m] = *(const bf16x8*)(Alds + byte);
    }
    #pragma unroll
    for(int j = 0; j < 2; j++){
      int col = (w*2+j)*16 + lrow;
      bf16x8 bfr = *(const bf16x8*)(wt + col*128 + ks*32 + lk*8);
      #pragma unroll
      for(int m = 0; m < 4; m++)
        acc[m][j] = __builtin_amdgcn_mfma_f32_16x16x32_bf16(af[m], bfr, acc[m][j], 0,0,0);
    }
  }
  #pragma unroll
  for(int j = 0; j < 2; j++){
    int col = (w*2+j)*16 + lrow;
    float bv = bias[col];
    #pragma unroll
    for(int m = 0; m < 4; m++){
      int rb = row0 + m*16 + lk*4;
      #pragma unroll
      for(int rr = 0; rr < 4; rr++){
        int row = rb + rr;
        if(row < n) hraw[(long)row*DD + col] = f2bf(acc[m][j][rr] + bv);
      }
    }
  }
}

// ---------------- BN stats over h_raw ----------------

__global__ __launch_bounds__(256) void stats_k(const short* hraw, float* sum,
                                               float* sumsq, int n){
  __shared__ float ls[256], ls2[256];
  int t = threadIdx.x;
  int col = t & 127, half = t >> 7;
  int rpb = (n + gridDim.x - 1) / gridDim.x;
  int r0 = blockIdx.x*rpb;
  int r1 = r0 + rpb; if(r1 > n) r1 = n;
  float s = 0.f, s2 = 0.f;
  for(int r = r0 + half; r < r1; r += 2){
    float v = bf2f(hraw[(long)r*DD + col]);
    s += v; s2 += v*v;
  }
  ls[t] = s; ls2[t] = s2;
  __syncthreads();
  if(t < 128){
    s = ls[t] + ls[t+128]; s2 = ls2[t] + ls2[t+128];
    atomicAdd(&sum[col], s); atomicAdd(&sumsq[col], s2);
  }
}

__global__ void bnfin_k(const float* sum, const float* sumsq, const float* gamma,
                        const float* beta, float* scale, float* shift, int n){
  int c = threadIdx.x;
  if(c >= DD) return;
  float inv_n = 1.0f/(float)n;
  float mean = sum[c]*inv_n;
  float var = sumsq[c]*inv_n - mean*mean;
  float sc = gamma[c]*rsqrtf(var + 1e-5f);
  scale[c] = sc;
  shift[c] = beta[c] - mean*sc;
}

// ---------------- GEMM 2: [h_act | H] @ [Wz|Wr] -> Z (bf16), RH = sigmoid(.)*H (bf16) --

__global__ __launch_bounds__(256) void gemm_zr_k(const short* hraw, const float* H,
    const short* wtzr, const float* scale, const float* shift, const float* prelu,
    const float* bz, const float* br, short* Z, short* RH, int n){
  __shared__ char Alds[64*512];  // 64 rows x 256 bf16, swizzled
  const int t = threadIdx.x;
  const int row0 = blockIdx.x*64;
  const float pa = prelu[0];
  for(int u = t; u < 2048; u += 256){
    int r = u >> 5, ku = u & 31;
    int grow = row0 + r;
    bf16x8 wv = {0,0,0,0,0,0,0,0};
    if(ku < 16){
      if(grow < n){
        bf16x8 hv = *(const bf16x8*)(hraw + (long)grow*DD + ku*8);
        #pragma unroll
        for(int j = 0; j < 8; j++){
          int c = ku*8 + j;
          float f = bf2f(hv[j])*scale[c] + shift[c];
          f = f > 0.f ? f : pa*f;
          wv[j] = f2bf(f);
        }
      }
    } else {
      if(grow < n){
        const f32x4* p = (const f32x4*)(H + (long)grow*DD + (ku-16)*8);
        f32x4 a = p[0], b = p[1];
        #pragma unroll
        for(int j = 0; j < 4; j++){ wv[j] = f2bf(a[j]); wv[4+j] = f2bf(b[j]); }
      }
    }
    int byte = r*512 + ((ku*16) ^ ((r&7)<<4));
    *(bf16x8*)(Alds + byte) = wv;
  }
  __syncthreads();
  const int w = t >> 6, l = t & 63;
  const int lrow = l & 15, lk = l >> 4;
  f32x4 acc[4][4];
  #pragma unroll
  for(int m = 0; m < 4; m++) for(int j = 0; j < 4; j++) acc[m][j] = (f32x4){0,0,0,0};
  #pragma unroll
  for(int ks = 0; ks < 8; ks++){
    bf16x8 af[4];
    #pragma unroll
    for(int m = 0; m < 4; m++){
      int r = m*16 + lrow;
      int byte = r*512 + ((ks*64 + lk*16) ^ ((r&7)<<4));
      af[m] = *(const bf16x8*)(Alds + byte);
    }
    #pragma unroll
    for(int j = 0; j < 4; j++){
      int col = (w*4+j)*16 + lrow;
      bf16x8 bfr = *(const bf16x8*)(wtzr + (long)col*256 + ks*32 + lk*8);
      #pragma unroll
      for(int m = 0; m < 4; m++)
        acc[m][j] = __builtin_amdgcn_mfma_f32_16x16x32_bf16(af[m], bfr, acc[m][j], 0,0,0);
    }
  }
  #pragma unroll
  for(int j = 0; j < 4; j++){
    int col256 = (w*4+j)*16 + lrow;
    if(col256 < 128){
      float bv = bz[col256];
      #pragma unroll
      for(int m = 0; m < 4; m++){
        #pragma unroll
        for(int rr = 0; rr < 4; rr++){
          int row = row0 + m*16 + lk*4 + rr;
          if(row < n) Z[(long)row*DD + col256] = f2bf(sigm(acc[m][j][rr] + bv));
        }
      }
    } else {
      int col = col256 - 128;
      float bv = br[col];
      #pragma unroll
      for(int m = 0; m < 4; m++){
        #pragma unroll
        for(int rr = 0; rr < 4; rr++){
          int row = row0 + m*16 + lk*4 + rr;
          if(row < n){
            float rv = sigm(acc[m][j][rr] + bv);
            float hv = H[(long)row*DD + col];
            RH[(long)row*DD + col] = f2bf(rv*hv);
          }
        }
      }
    }
  }
}

// ---------------- GEMM 3: [h_act | RH] @ Wh -> H_tilde; out = Z*H + (1-Z)*tanh -------

__global__ __launch_bounds__(256) void gemm_ht_k(const short* hraw, const short* RH,
    const short* wth, const float* scale, const float* shift, const float* prelu,
    const float* bh, const short* Z, const float* H, float* out, int n){
  __shared__ char Alds[64*512];
  const int t = threadIdx.x;
  const int row0 = blockIdx.x*64;
  const float pa = prelu[0];
  for(int u = t; u < 2048; u += 256){
    int r = u >> 5, ku = u & 31;
    int grow = row0 + r;
    bf16x8 wv = {0,0,0,0,0,0,0,0};
    if(ku < 16){
      if(grow < n){
        bf16x8 hv = *(const bf16x8*)(hraw + (long)grow*DD + ku*8);
        #pragma unroll
        for(int j = 0; j < 8; j++){
          int c = ku*8 + j;
          float f = bf2f(hv[j])*scale[c] + shift[c];
          f = f > 0.f ? f : pa*f;
          wv[j] = f2bf(f);
        }
      }
    } else {
      if(grow < n) wv = *(const bf16x8*)(RH + (long)grow*DD + (ku-16)*8);
    }
    int byte = r*512 + ((ku*16) ^ ((r&7)<<4));
    *(bf16x8*)(Alds + byte) = wv;
  }
  __syncthreads();
  const int w = t >> 6, l = t & 63;
  const int lrow = l & 15, lk = l >> 4;
  f32x4 acc[4][2];
  #pragma unroll
  for(int m = 0; m < 4; m++) for(int j = 0; j < 2; j++) acc[m][j] = (f32x4){0,0,0,0};
  #pragma unroll
  for(int ks = 0; ks < 8; ks++){
    bf16x8 af[4];
    #pragma unroll
    for(int m = 0; m < 4; m++){
      int r = m*16 + lrow;
      int byte = r*512 + ((ks*64 + lk*16) ^ ((r&7)<<4));
      af[m] = *(const bf16x8*)(Alds + byte);
    }
    #pragma unroll
    for(int j = 0; j < 2; j++){
      int col = (w*2+j)*16 + lrow;
      bf16x8 bfr = *(const bf16x8*)(wth + (long)col*256 + ks*32 + lk*8);
      #pragma unroll
      for(int m = 0; m < 4; m++)
        acc[m][j] = __builtin_amdgcn_mfma_f32_16x16x32_bf16(af[m], bfr, acc[m][j], 0,0,0);
    }
  }
  #pragma unroll
  for(int j = 0; j < 2; j++){
    int col = (w*2+j)*16 + lrow;
    float bv = bh[col];
    #pragma unroll
    for(int m = 0; m < 4; m++){
      #pragma unroll
      for(int rr = 0; rr < 4; rr++){
        int row = row0 + m*16 + lk*4 + rr;
        if(row < n){
          float ht = tanh_f(acc[m][j][rr] + bv);
          float z = bf2f(Z[(long)row*DD + col]);
          float Hv = H[(long)row*DD + col];
          out[(long)row*DD + col] = z*Hv + (1.f - z)*ht;
        }
      }
    }
  }
}

// ---------------- launch ----------------

extern "C" void kernel_launch(void* const* d_in, const int* in_sizes, int n_in,
                              void* d_out, int out_size, void* d_ws, size_t ws_size,
                              hipStream_t stream){
  const float* x     = (const float*)d_in[0];
  const int*   e32   = (const int*)d_in[1];
  const float* H     = (const float*)d_in[2];
  const float* Wg    = (const float*)d_in[3];
  const float* bg    = (const float*)d_in[4];
  const float* gamma = (const float*)d_in[5];
  const float* beta  = (const float*)d_in[6];
  const float* prelu = (const float*)d_in[7];
  const float* Wz    = (const float*)d_in[8];
  const float* bz    = (const float*)d_in[9];
  const float* Wr    = (const float*)d_in[10];
  const float* br    = (const float*)d_in[11];
  const float* Wh    = (const float*)d_in[12];
  const float* bh    = (const float*)d_in[13];
  float* out = (float*)d_out;
  const int n = in_sizes[0] / DD;
  const int e = in_sizes[1] / 2;
  const int nb = (n + CHUNK - 1) / CHUNK;

  char* ws = (char*)d_ws;
  size_t o = 0;
  auto alloc = [&](size_t bytes)->char*{
    char* p = ws + o; o = (o + bytes + 255) & ~(size_t)255; return p;
  };
  int*   deg    = (int*)  alloc(4L*n);
  float* dinv   = (float*)alloc(4L*n);
  int*   flag   = (int*)  alloc(256);
  float* sum    = (float*)alloc(512);
  float* sumsq  = (float*)alloc(512);
  float* scale  = (float*)alloc(512);
  float* shift  = (float*)alloc(512);
  int*   bsum   = (int*)  alloc(4L*nb);
  int*   offs   = (int*)  alloc(4L*n);
  int*   cursor = (int*)  alloc(4L*n);
  int*   srcs   = (int*)  alloc(4L*e);
  short* wtg    = (short*)alloc(128L*128*2);
  short* wtzr   = (short*)alloc(256L*256*2);
  short* wth    = (short*)alloc(128L*256*2);
  short* aggb   = (short*)alloc(2L*n*DD);
  short* hraw   = (short*)alloc(2L*n*DD);
  short* Zb     = (short*)alloc(2L*n*DD);
  short* RHb    = (short*)alloc(2L*n*DD);

  zero_stats_k<<<1, 256, 0, stream>>>(sum, sumsq, flag);
  init_deg_k<<<(n+255)/256, 256, 0, stream>>>(deg, n);
  flag_k<<<(e+255)/256, 256, 0, stream>>>(e32, flag, e);
  deg_k<<<(e+255)/256, 256, 0, stream>>>(e32, flag, deg, e, n);
  dinv_k<<<(n+255)/256, 256, 0, stream>>>(deg, dinv, n);
  cvtw_k<<<(128*128+255)/256, 256, 0, stream>>>(Wg, wtg, 128, 128);
  cvtw_k<<<(256*128+255)/256, 256, 0, stream>>>(Wz, wtzr, 256, 128);
  cvtw_k<<<(256*128+255)/256, 256, 0, stream>>>(Wr, wtzr + 128*256, 256, 128);
  cvtw_k<<<(256*128+255)/256, 256, 0, stream>>>(Wh, wth, 256, 128);
  scanA_k<<<nb, 256, 0, stream>>>(deg, bsum, n);
  scanB_k<<<1, 64, 0, stream>>>(bsum, nb);
  scanC_k<<<nb, 256, 0, stream>>>(deg, bsum, offs, cursor, n);
  fill_k<<<(e+255)/256, 256, 0, stream>>>(e32, flag, cursor, srcs, e, n);
  gather_k<<<(n+7)/8, 256, 0, stream>>>(x, dinv, offs, deg, srcs, aggb, n);
  const int gb = (n + 63)/64;
  gemm_h_k<<<gb, 256, 0, stream>>>(aggb, wtg, bg, hraw, n);
  stats_k<<<1024, 256, 0, stream>>>(hraw, sum, sumsq, n);
  bnfin_k<<<1, 128, 0, stream>>>(sum, sumsq, gamma, beta, scale, shift, n);
  gemm_zr_k<<<gb, 256, 0, stream>>>(hraw, H, wtzr, scale, shift, prelu, bz, br, Zb, RHb, n);
  gemm_ht_k<<<gb, 256, 0, stream>>>(hraw, RHb, wth, scale, shift, prelu, bh, Zb, H, out, n);
}

// Round 3
// 350.376 us; speedup vs baseline: 3.9559x; 1.1199x over previous
//
#include <hip/hip_runtime.h>
#include <hip/hip_bf16.h>
#include <stdint.h>

#define DD 128
#define CHUNK 1024

typedef short bf16x8 __attribute__((ext_vector_type(8)));
typedef short bf16x4 __attribute__((ext_vector_type(4)));
typedef float f32x4 __attribute__((ext_vector_type(4)));

__device__ __forceinline__ short f2bf(float f){
  union { float f; uint32_t u; } v; v.f = f;
  uint32_t r = v.u + 0x7fffu + ((v.u >> 16) & 1u);
  return (short)(r >> 16);
}
__device__ __forceinline__ float bf2f(short s){
  union { uint32_t u; float f; } v; v.u = ((uint32_t)(uint16_t)s) << 16;
  return v.f;
}
__device__ __forceinline__ float sigm(float x){ return 1.0f/(1.0f + __expf(-x)); }
__device__ __forceinline__ float tanh_f(float x){ return 1.0f - 2.0f/(__expf(2.0f*x) + 1.0f); }

// ---------------- prep kernels ----------------

__global__ void prep0_k(int* deg, float* sum, float* sumsq, int* flag, int n){
  int i = blockIdx.x*256 + threadIdx.x;
  if(i < n) deg[i] = 1;
  if(blockIdx.x == 0){
    int t = threadIdx.x;
    if(t < DD){ sum[t] = 0.f; sumsq[t] = 0.f; }
    if(t == 0) *flag = 0;
  }
}

// Detect edge_index storage: int64 buffers have zero odd int32 words.
__global__ void flag_k(const int* e32, int* flag, int e){
  int i = blockIdx.x*256 + threadIdx.x;
  if(i < e && e32[2*i+1] != 0) *flag = 1;   // benign race: all write 1
}

__device__ __forceinline__ int eidx(const int* e32, int is32, long pos, int n){
  int v = is32 ? e32[pos] : e32[2*pos];
  return v < 0 ? 0 : (v >= n ? n-1 : v);
}

__global__ void deg_k(const int* e32, const int* flag, int* deg, int e, int n){
  int i = blockIdx.x*256 + threadIdx.x;
  if(i >= e) return;
  int is32 = *flag;
  int c = eidx(e32, is32, (long)e + i, n);  // cols = targets
  atomicAdd(&deg[c], 1);
}

__global__ void dinv_k(const int* deg, float* dinv, int n){
  int i = blockIdx.x*256 + threadIdx.x;
  if(i < n) dinv[i] = rsqrtf((float)deg[i]);
}

// Wt[n*K + k] = bf16(W[k*Nout + n])   (transpose + convert)
__global__ void cvtw_k(const float* w, short* wt, int K, int Nout){
  int t = blockIdx.x*256 + threadIdx.x;
  if(t >= K*Nout) return;
  int nn = t / K, k = t - nn*K;
  wt[t] = f2bf(w[k*Nout + nn]);
}

// ---------------- CSR build ----------------

__global__ __launch_bounds__(256) void scanA_k(const int* deg, int* bsum, int n){
  __shared__ int ls[256];
  int b = blockIdx.x, t = threadIdx.x;
  int base = b*CHUNK + t*4;
  int s = 0;
  #pragma unroll
  for(int j = 0; j < 4; j++){ int i = base + j; if(i < n) s += deg[i] - 1; }
  ls[t] = s; __syncthreads();
  for(int off = 128; off > 0; off >>= 1){
    if(t < off) ls[t] += ls[t+off];
    __syncthreads();
  }
  if(t == 0) bsum[b] = ls[0];
}

__global__ void scanB_k(int* bsum, int nb){
  if(threadIdx.x == 0){
    int acc = 0;
    for(int i = 0; i < nb; i++){ int v = bsum[i]; bsum[i] = acc; acc += v; }
  }
}

__global__ __launch_bounds__(256) void scanC_k(const int* deg, const int* bsum,
                                               int* off, int* cursor, int n){
  __shared__ int ls[256];
  int b = blockIdx.x, t = threadIdx.x;
  int base = b*CHUNK + t*4;
  int v[4]; int s = 0;
  #pragma unroll
  for(int j = 0; j < 4; j++){ int i = base + j; v[j] = (i < n) ? deg[i]-1 : 0; s += v[j]; }
  ls[t] = s; __syncthreads();
  for(int d = 1; d < 256; d <<= 1){
    int tmp = (t >= d) ? ls[t-d] : 0;
    __syncthreads();
    ls[t] += tmp;
    __syncthreads();
  }
  int run = bsum[b] + ls[t] - s;   // exclusive prefix
  #pragma unroll
  for(int j = 0; j < 4; j++){
    int i = base + j;
    if(i < n){ off[i] = run; cursor[i] = run; run += v[j]; }
  }
}

__global__ void fill_k(const int* e32, const int* flag, int* cursor, int* srcs,
                       int e, int n){
  int i = blockIdx.x*256 + threadIdx.x;
  if(i >= e) return;
  int is32 = *flag;
  int r = eidx(e32, is32, i, n);
  int c = eidx(e32, is32, (long)e + i, n);
  int slot = atomicAdd(&cursor[c], 1);
  srcs[slot] = r;
}

// ---------------- fused GCN: CSR gather -> LDS -> GEMM -> hraw + BN partial stats ----

__global__ __launch_bounds__(256) void gcn_k(const float* x, const float* dinv,
    const int* offs, const int* deg, const int* srcs, const short* wt,
    const float* bias, short* hraw, float* sum, float* sumsq, int n){
  __shared__ char Alds[64*256];  // 64 rows x 128 bf16, XOR-swizzled
  const int t = threadIdx.x;
  const int row0 = blockIdx.x*64;
  const int g = t >> 5, d4 = t & 31;
  for(int rr = 0; rr < 8; rr++){
    int row = g*8 + rr;
    int node = row0 + row;
    bf16x4 o4 = {0,0,0,0};
    if(node < n){
      float di = dinv[node];
      f32x4 acc = *(const f32x4*)(x + (long)node*DD + d4*4);
      acc *= di*di;
      int o0 = offs[node], cnt = deg[node] - 1;
      for(int j = 0; j < cnt; j++){
        int r = srcs[o0 + j];
        float nrm = di*dinv[r];
        f32x4 v = *(const f32x4*)(x + (long)r*DD + d4*4);
        acc += v*nrm;
      }
      #pragma unroll
      for(int j = 0; j < 4; j++) o4[j] = f2bf(acc[j]);
    }
    int byte = row*256 + ((d4*8) ^ ((row&7)<<4));
    *(bf16x4*)(Alds + byte) = o4;
  }
  __syncthreads();
  const int w = t >> 6, l = t & 63;
  const int lrow = l & 15, lk = l >> 4;
  f32x4 acc[4][2];
  #pragma unroll
  for(int m = 0; m < 4; m++) for(int j = 0; j < 2; j++) acc[m][j] = (f32x4){0,0,0,0};
  #pragma unroll
  for(int ks = 0; ks < 4; ks++){
    bf16x8 af[4];
    #pragma unroll
    for(int m = 0; m < 4; m++){
      int r = m*16 + lrow;
      int byte = r*256 + ((ks*64 + lk*16) ^ ((r&7)<<4));
      af[m] = *(const bf16x8*)(Alds + byte);
    }
    #pragma unroll
    for(int j = 0; j < 2; j++){
      int col = (w*2+j)*16 + lrow;
      bf16x8 bfr = *(const bf16x8*)(wt + col*128 + ks*32 + lk*8);
      #pragma unroll
      for(int m = 0; m < 4; m++)
        acc[m][j] = __builtin_amdgcn_mfma_f32_16x16x32_bf16(af[m], bfr, acc[m][j], 0,0,0);
    }
  }
  #pragma unroll
  for(int j = 0; j < 2; j++){
    int col = (w*2+j)*16 + lrow;
    float bv = bias[col];
    float s = 0.f, s2 = 0.f;
    #pragma unroll
    for(int m = 0; m < 4; m++){
      int rb = row0 + m*16 + lk*4;
      #pragma unroll
      for(int rr = 0; rr < 4; rr++){
        int row = rb + rr;
        if(row < n){
          float h = acc[m][j][rr] + bv;
          hraw[(long)row*DD + col] = f2bf(h);
          s += h; s2 += h*h;
        }
      }
    }
    s  += __shfl_xor(s, 16);  s  += __shfl_xor(s, 32);
    s2 += __shfl_xor(s2, 16); s2 += __shfl_xor(s2, 32);
    if(lk == 0){
      atomicAdd(&sum[col], s);
      atomicAdd(&sumsq[col], s2);
    }
  }
}

__global__ void bnfin_k(const float* sum, const float* sumsq, const float* gamma,
                        const float* beta, float* scale, float* shift, int n){
  int c = threadIdx.x;
  if(c >= DD) return;
  float inv_n = 1.0f/(float)n;
  float mean = sum[c]*inv_n;
  float var = sumsq[c]*inv_n - mean*mean;
  float sc = gamma[c]*rsqrtf(var + 1e-5f);
  scale[c] = sc;
  shift[c] = beta[c] - mean*sc;
}

// ---------------- fused GRU ----------------

__global__ __launch_bounds__(256) void gru_k(const short* hraw, const float* H,
    const short* wtzr, const short* wth, const float* scale, const float* shift,
    const float* prelu, const float* bz, const float* br, const float* bh,
    float* out, int n){
  __shared__ char Alds[64*512];     // [64][256] bf16, XOR-swizzled: [h_act | H] -> [h_act | R*H]
  __shared__ short Zl[64][136];     // Z bf16, +8 pad
  const int t = threadIdx.x;
  const int row0 = blockIdx.x*64;
  const float pa = prelu[0];
  for(int u = t; u < 2048; u += 256){
    int r = u >> 5, ku = u & 31;
    int grow = row0 + r;
    bf16x8 wv = {0,0,0,0,0,0,0,0};
    if(ku < 16){
      if(grow < n){
        bf16x8 hv = *(const bf16x8*)(hraw + (long)grow*DD + ku*8);
        #pragma unroll
        for(int j = 0; j < 8; j++){
          int c = ku*8 + j;
          float f = bf2f(hv[j])*scale[c] + shift[c];
          f = f > 0.f ? f : pa*f;
          wv[j] = f2bf(f);
        }
      }
    } else {
      if(grow < n){
        const f32x4* p = (const f32x4*)(H + (long)grow*DD + (ku-16)*8);
        f32x4 a = p[0], b = p[1];
        #pragma unroll
        for(int j = 0; j < 4; j++){ wv[j] = f2bf(a[j]); wv[4+j] = f2bf(b[j]); }
      }
    }
    int byte = r*512 + ((ku*16) ^ ((r&7)<<4));
    *(bf16x8*)(Alds + byte) = wv;
  }
  __syncthreads();
  const int w = t >> 6, l = t & 63;
  const int lrow = l & 15, lk = l >> 4;
  f32x4 acc[4][4];
  #pragma unroll
  for(int m = 0; m < 4; m++) for(int j = 0; j < 4; j++) acc[m][j] = (f32x4){0,0,0,0};
  #pragma unroll
  for(int ks = 0; ks < 8; ks++){
    bf16x8 af[4];
    #pragma unroll
    for(int m = 0; m < 4; m++){
      int r = m*16 + lrow;
      int byte = r*512 + ((ks*64 + lk*16) ^ ((r&7)<<4));
      af[m] = *(const bf16x8*)(Alds + byte);
    }
    #pragma unroll
    for(int j = 0; j < 4; j++){
      int col = w*64 + j*16 + lrow;
      bf16x8 bfr = *(const bf16x8*)(wtzr + (long)col*256 + ks*32 + lk*8);
      #pragma unroll
      for(int m = 0; m < 4; m++)
        acc[m][j] = __builtin_amdgcn_mfma_f32_16x16x32_bf16(af[m], bfr, acc[m][j], 0,0,0);
    }
  }
  __syncthreads();   // all ZR reads of Alds complete
  #pragma unroll
  for(int j = 0; j < 4; j++){
    int col256 = w*64 + j*16 + lrow;
    if(col256 < 128){
      float bv = bz[col256];
      #pragma unroll
      for(int m = 0; m < 4; m++){
        #pragma unroll
        for(int rr = 0; rr < 4; rr++){
          int row = m*16 + lk*4 + rr;
          Zl[row][col256] = f2bf(sigm(acc[m][j][rr] + bv));
        }
      }
    } else {
      int col = col256 - 128;
      float bv = br[col];
      #pragma unroll
      for(int m = 0; m < 4; m++){
        #pragma unroll
        for(int rr = 0; rr < 4; rr++){
          int row = m*16 + lk*4 + rr;
          int grow = row0 + row;
          if(grow < n){
            float rv = sigm(acc[m][j][rr] + bv);
            float hv = H[(long)grow*DD + col];
            int byte = row*512 + ((2*(128+col)) ^ ((row&7)<<4));
            *(short*)(Alds + byte) = f2bf(rv*hv);
          }
        }
      }
    }
  }
  __syncthreads();   // RH + Z staged
  f32x4 acc2[4][2];
  #pragma unroll
  for(int m = 0; m < 4; m++) for(int j = 0; j < 2; j++) acc2[m][j] = (f32x4){0,0,0,0};
  #pragma unroll
  for(int ks = 0; ks < 8; ks++){
    bf16x8 af[4];
    #pragma unroll
    for(int m = 0; m < 4; m++){
      int r = m*16 + lrow;
      int byte = r*512 + ((ks*64 + lk*16) ^ ((r&7)<<4));
      af[m] = *(const bf16x8*)(Alds + byte);
    }
    #pragma unroll
    for(int j = 0; j < 2; j++){
      int col = w*32 + j*16 + lrow;
      bf16x8 bfr = *(const bf16x8*)(wth + (long)col*256 + ks*32 + lk*8);
      #pragma unroll
      for(int m = 0; m < 4; m++)
        acc2[m][j] = __builtin_amdgcn_mfma_f32_16x16x32_bf16(af[m], bfr, acc2[m][j], 0,0,0);
    }
  }
  #pragma unroll
  for(int j = 0; j < 2; j++){
    int col = w*32 + j*16 + lrow;
    float bv = bh[col];
    #pragma unroll
    for(int m = 0; m < 4; m++){
      #pragma unroll
      for(int rr = 0; rr < 4; rr++){
        int row = m*16 + lk*4 + rr;
        int grow = row0 + row;
        if(grow < n){
          float ht = tanh_f(acc2[m][j][rr] + bv);
          float z = bf2f(Zl[row][col]);
          float Hv = H[(long)grow*DD + col];
          out[(long)grow*DD + col] = z*Hv + (1.f - z)*ht;
        }
      }
    }
  }
}

// ---------------- launch ----------------

extern "C" void kernel_launch(void* const* d_in, const int* in_sizes, int n_in,
                              void* d_out, int out_size, void* d_ws, size_t ws_size,
                              hipStream_t stream){
  const float* x     = (const float*)d_in[0];
  const int*   e32   = (const int*)d_in[1];
  const float* H     = (const float*)d_in[2];
  const float* Wg    = (const float*)d_in[3];
  const float* bg    = (const float*)d_in[4];
  const float* gamma = (const float*)d_in[5];
  const float* beta  = (const float*)d_in[6];
  const float* prelu = (const float*)d_in[7];
  const float* Wz    = (const float*)d_in[8];
  const float* bz    = (const float*)d_in[9];
  const float* Wr    = (const float*)d_in[10];
  const float* br    = (const float*)d_in[11];
  const float* Wh    = (const float*)d_in[12];
  const float* bh    = (const float*)d_in[13];
  float* out = (float*)d_out;
  const int n = in_sizes[0] / DD;
  const int e = in_sizes[1] / 2;
  const int nb = (n + CHUNK - 1) / CHUNK;

  char* ws = (char*)d_ws;
  size_t o = 0;
  auto alloc = [&](size_t bytes)->char*{
    char* p = ws + o; o = (o + bytes + 255) & ~(size_t)255; return p;
  };
  int*   deg    = (int*)  alloc(4L*n);
  float* dinv   = (float*)alloc(4L*n);
  int*   flag   = (int*)  alloc(256);
  float* sum    = (float*)alloc(512);
  float* sumsq  = (float*)alloc(512);
  float* scale  = (float*)alloc(512);
  float* shift  = (float*)alloc(512);
  int*   bsum   = (int*)  alloc(4L*nb);
  int*   offs   = (int*)  alloc(4L*n);
  int*   cursor = (int*)  alloc(4L*n);
  int*   srcs   = (int*)  alloc(4L*e);
  short* wtg    = (short*)alloc(128L*128*2);
  short* wtzr   = (short*)alloc(256L*256*2);
  short* wth    = (short*)alloc(128L*256*2);
  short* hraw   = (short*)alloc(2L*n*DD);

  prep0_k<<<(n+255)/256, 256, 0, stream>>>(deg, sum, sumsq, flag, n);
  flag_k<<<(e+255)/256, 256, 0, stream>>>(e32, flag, e);
  deg_k<<<(e+255)/256, 256, 0, stream>>>(e32, flag, deg, e, n);
  dinv_k<<<(n+255)/256, 256, 0, stream>>>(deg, dinv, n);
  cvtw_k<<<(128*128+255)/256, 256, 0, stream>>>(Wg, wtg, 128, 128);
  cvtw_k<<<(256*128+255)/256, 256, 0, stream>>>(Wz, wtzr, 256, 128);
  cvtw_k<<<(256*128+255)/256, 256, 0, stream>>>(Wr, wtzr + 128*256, 256, 128);
  cvtw_k<<<(256*128+255)/256, 256, 0, stream>>>(Wh, wth, 256, 128);
  scanA_k<<<nb, 256, 0, stream>>>(deg, bsum, n);
  scanB_k<<<1, 64, 0, stream>>>(bsum, nb);
  scanC_k<<<nb, 256, 0, stream>>>(deg, bsum, offs, cursor, n);
  fill_k<<<(e+255)/256, 256, 0, stream>>>(e32, flag, cursor, srcs, e, n);
  const int gb = (n + 63)/64;
  gcn_k<<<gb, 256, 0, stream>>>(x, dinv, offs, deg, srcs, wtg, bg, hraw, sum, sumsq, n);
  bnfin_k<<<1, 128, 0, stream>>>(sum, sumsq, gamma, beta, scale, shift, n);
  gru_k<<<gb, 256, 0, stream>>>(hraw, H, wtzr, wth, scale, shift, prelu, bz, br, bh, out, n);
}

// Round 4
// 349.928 us; speedup vs baseline: 3.9609x; 1.0013x over previous
//
#include <hip/hip_runtime.h>
#include <hip/hip_bf16.h>
#include <stdint.h>

#define DD 128
#define CHUNK 1024

typedef short bf16x8 __attribute__((ext_vector_type(8)));
typedef short bf16x4 __attribute__((ext_vector_type(4)));
typedef float f32x4 __attribute__((ext_vector_type(4)));

__device__ __forceinline__ short f2bf(float f){
  union { float f; uint32_t u; } v; v.f = f;
  uint32_t r = v.u + 0x7fffu + ((v.u >> 16) & 1u);
  return (short)(r >> 16);
}
__device__ __forceinline__ float bf2f(short s){
  union { uint32_t u; float f; } v; v.u = ((uint32_t)(uint16_t)s) << 16;
  return v.f;
}
__device__ __forceinline__ float sigm(float x){ return 1.0f/(1.0f + __expf(-x)); }
__device__ __forceinline__ float tanh_f(float x){ return 1.0f - 2.0f/(__expf(2.0f*x) + 1.0f); }

// ---------------- prep kernels ----------------

__global__ void prep0_k(int* deg, float* sum, float* sumsq, int* flag, int n){
  int i = blockIdx.x*256 + threadIdx.x;
  if(i < n) deg[i] = 1;
  if(blockIdx.x == 0){
    int t = threadIdx.x;
    if(t < DD){ sum[t] = 0.f; sumsq[t] = 0.f; }
    if(t == 0) *flag = 0;
  }
}

// Detect edge_index storage: int64 buffers have zero odd int32 words.
__global__ void flag_k(const int* e32, int* flag, int e){
  int i = blockIdx.x*256 + threadIdx.x;
  if(i < e && e32[2*i+1] != 0) *flag = 1;   // benign race: all write 1
}

__device__ __forceinline__ int eidx(const int* e32, int is32, long pos, int n){
  int v = is32 ? e32[pos] : e32[2*pos];
  return v < 0 ? 0 : (v >= n ? n-1 : v);
}

__global__ void deg_k(const int* e32, const int* flag, int* deg, int e, int n){
  int i = blockIdx.x*256 + threadIdx.x;
  if(i >= e) return;
  int is32 = *flag;
  int c = eidx(e32, is32, (long)e + i, n);  // cols = targets
  atomicAdd(&deg[c], 1);
}

__global__ void dinv_k(const int* deg, float* dinv, int n){
  int i = blockIdx.x*256 + threadIdx.x;
  if(i < n) dinv[i] = rsqrtf((float)deg[i]);
}

// Wt[n*K + k] = bf16(W[k*Nout + n])   (transpose + convert)
__global__ void cvtw_k(const float* w, short* wt, int K, int Nout){
  int t = blockIdx.x*256 + threadIdx.x;
  if(t >= K*Nout) return;
  int nn = t / K, k = t - nn*K;
  wt[t] = f2bf(w[k*Nout + nn]);
}

// ---------------- CSR build ----------------

__global__ __launch_bounds__(256) void scanA_k(const int* deg, int* bsum, int n){
  __shared__ int ls[256];
  int b = blockIdx.x, t = threadIdx.x;
  int base = b*CHUNK + t*4;
  int s = 0;
  #pragma unroll
  for(int j = 0; j < 4; j++){ int i = base + j; if(i < n) s += deg[i] - 1; }
  ls[t] = s; __syncthreads();
  for(int off = 128; off > 0; off >>= 1){
    if(t < off) ls[t] += ls[t+off];
    __syncthreads();
  }
  if(t == 0) bsum[b] = ls[0];
}

__global__ void scanB_k(int* bsum, int nb){
  if(threadIdx.x == 0){
    int acc = 0;
    for(int i = 0; i < nb; i++){ int v = bsum[i]; bsum[i] = acc; acc += v; }
  }
}

__global__ __launch_bounds__(256) void scanC_k(const int* deg, const int* bsum,
                                               int* off, int* cursor, int n){
  __shared__ int ls[256];
  int b = blockIdx.x, t = threadIdx.x;
  int base = b*CHUNK + t*4;
  int v[4]; int s = 0;
  #pragma unroll
  for(int j = 0; j < 4; j++){ int i = base + j; v[j] = (i < n) ? deg[i]-1 : 0; s += v[j]; }
  ls[t] = s; __syncthreads();
  for(int d = 1; d < 256; d <<= 1){
    int tmp = (t >= d) ? ls[t-d] : 0;
    __syncthreads();
    ls[t] += tmp;
    __syncthreads();
  }
  int run = bsum[b] + ls[t] - s;   // exclusive prefix
  #pragma unroll
  for(int j = 0; j < 4; j++){
    int i = base + j;
    if(i < n){ off[i] = run; cursor[i] = run; run += v[j]; }
  }
}

__global__ void fill_k(const int* e32, const int* flag, int* cursor, int* srcs,
                       int e, int n){
  int i = blockIdx.x*256 + threadIdx.x;
  if(i >= e) return;
  int is32 = *flag;
  int r = eidx(e32, is32, i, n);
  int c = eidx(e32, is32, (long)e + i, n);
  int slot = atomicAdd(&cursor[c], 1);
  srcs[slot] = r;
}

// ---------------- fused GCN: CSR gather -> LDS -> GEMM -> hraw + BN partial stats ----
// Gather: one 64-lane wave per node; halves process even/odd edges in
// predicated batches of 4 -> 8 concurrent x-row load chains per wave.

__global__ __launch_bounds__(256) void gcn_k(const float* x, const float* dinv,
    const int* offs, const int* deg, const int* srcs, const short* wt,
    const float* bias, short* hraw, float* sum, float* sumsq, int n){
  __shared__ char Alds[64*256];  // 64 rows x 128 bf16, XOR-swizzled
  const int t = threadIdx.x;
  const int row0 = blockIdx.x*64;
  const int wv = t >> 6, l = t & 63;
  const int half = l >> 5, d4 = l & 31;
  for(int rr = 0; rr < 16; rr++){
    int row = wv*16 + rr;
    int node = row0 + row;
    f32x4 acc = {0,0,0,0};
    if(node < n){            // wave-uniform branch
      float di = dinv[node];
      int o0 = offs[node], cnt = deg[node] - 1;
      if(half == 0){
        f32x4 sv = *(const f32x4*)(x + (long)node*DD + d4*4);
        acc = sv*(di*di);
      }
      for(int jb = half; jb < cnt; jb += 8){
        #pragma unroll
        for(int k = 0; k < 4; k++){
          int jj = jb + 2*k;
          bool ok = jj < cnt;
          int idx = o0 + (ok ? jj : (cnt - 1));   // clamped: always in-bounds
          int r = srcs[idx];
          float wk = ok ? di*dinv[r] : 0.f;
          f32x4 v = *(const f32x4*)(x + (long)r*DD + d4*4);
          acc += v*wk;
        }
      }
    }
    #pragma unroll
    for(int c = 0; c < 4; c++) acc[c] += __shfl_xor(acc[c], 32);
    if(half == 0){
      bf16x4 o4;
      #pragma unroll
      for(int c = 0; c < 4; c++) o4[c] = f2bf(acc[c]);
      int byte = row*256 + ((d4*8) ^ ((row&7)<<4));
      *(bf16x4*)(Alds + byte) = o4;
    }
  }
  __syncthreads();
  const int w = t >> 6, ll = t & 63;
  const int lrow = ll & 15, lk = ll >> 4;
  f32x4 acc[4][2];
  #pragma unroll
  for(int m = 0; m < 4; m++) for(int j = 0; j < 2; j++) acc[m][j] = (f32x4){0,0,0,0};
  #pragma unroll
  for(int ks = 0; ks < 4; ks++){
    bf16x8 af[4];
    #pragma unroll
    for(int m = 0; m < 4; m++){
      int r = m*16 + lrow;
      int byte = r*256 + ((ks*64 + lk*16) ^ ((r&7)<<4));
      af[m] = *(const bf16x8*)(Alds + byte);
    }
    #pragma unroll
    for(int j = 0; j < 2; j++){
      int col = (w*2+j)*16 + lrow;
      bf16x8 bfr = *(const bf16x8*)(wt + col*128 + ks*32 + lk*8);
      #pragma unroll
      for(int m = 0; m < 4; m++)
        acc[m][j] = __builtin_amdgcn_mfma_f32_16x16x32_bf16(af[m], bfr, acc[m][j], 0,0,0);
    }
  }
  #pragma unroll
  for(int j = 0; j < 2; j++){
    int col = (w*2+j)*16 + lrow;
    float bv = bias[col];
    float s = 0.f, s2 = 0.f;
    #pragma unroll
    for(int m = 0; m < 4; m++){
      int rb = row0 + m*16 + lk*4;
      #pragma unroll
      for(int rr = 0; rr < 4; rr++){
        int row = rb + rr;
        if(row < n){
          float h = acc[m][j][rr] + bv;
          hraw[(long)row*DD + col] = f2bf(h);
          s += h; s2 += h*h;
        }
      }
    }
    s  += __shfl_xor(s, 16);  s  += __shfl_xor(s, 32);
    s2 += __shfl_xor(s2, 16); s2 += __shfl_xor(s2, 32);
    if(lk == 0){
      atomicAdd(&sum[col], s);
      atomicAdd(&sumsq[col], s2);
    }
  }
}

__global__ void bnfin_k(const float* sum, const float* sumsq, const float* gamma,
                        const float* beta, float* scale, float* shift, int n){
  int c = threadIdx.x;
  if(c >= DD) return;
  float inv_n = 1.0f/(float)n;
  float mean = sum[c]*inv_n;
  float var = sumsq[c]*inv_n - mean*mean;
  float sc = gamma[c]*rsqrtf(var + 1e-5f);
  scale[c] = sc;
  shift[c] = beta[c] - mean*sc;
}

// ---------------- fused GRU ----------------

__global__ __launch_bounds__(256) void gru_k(const short* hraw, const float* H,
    const short* wtzr, const short* wth, const float* scale, const float* shift,
    const float* prelu, const float* bz, const float* br, const float* bh,
    float* out, int n){
  __shared__ char Alds[64*512];     // [64][256] bf16, XOR-swizzled: [h_act | H] -> [h_act | R*H]
  __shared__ short Zl[64][136];     // Z bf16, +8 pad
  const int t = threadIdx.x;
  const int row0 = blockIdx.x*64;
  const float pa = prelu[0];
  for(int u = t; u < 2048; u += 256){
    int r = u >> 5, ku = u & 31;
    int grow = row0 + r;
    bf16x8 wv = {0,0,0,0,0,0,0,0};
    if(ku < 16){
      if(grow < n){
        bf16x8 hv = *(const bf16x8*)(hraw + (long)grow*DD + ku*8);
        #pragma unroll
        for(int j = 0; j < 8; j++){
          int c = ku*8 + j;
          float f = bf2f(hv[j])*scale[c] + shift[c];
          f = f > 0.f ? f : pa*f;
          wv[j] = f2bf(f);
        }
      }
    } else {
      if(grow < n){
        const f32x4* p = (const f32x4*)(H + (long)grow*DD + (ku-16)*8);
        f32x4 a = p[0], b = p[1];
        #pragma unroll
        for(int j = 0; j < 4; j++){ wv[j] = f2bf(a[j]); wv[4+j] = f2bf(b[j]); }
      }
    }
    int byte = r*512 + ((ku*16) ^ ((r&7)<<4));
    *(bf16x8*)(Alds + byte) = wv;
  }
  __syncthreads();
  const int w = t >> 6, l = t & 63;
  const int lrow = l & 15, lk = l >> 4;
  f32x4 acc[4][4];
  #pragma unroll
  for(int m = 0; m < 4; m++) for(int j = 0; j < 4; j++) acc[m][j] = (f32x4){0,0,0,0};
  #pragma unroll
  for(int ks = 0; ks < 8; ks++){
    bf16x8 af[4];
    #pragma unroll
    for(int m = 0; m < 4; m++){
      int r = m*16 + lrow;
      int byte = r*512 + ((ks*64 + lk*16) ^ ((r&7)<<4));
      af[m] = *(const bf16x8*)(Alds + byte);
    }
    #pragma unroll
    for(int j = 0; j < 4; j++){
      int col = w*64 + j*16 + lrow;
      bf16x8 bfr = *(const bf16x8*)(wtzr + (long)col*256 + ks*32 + lk*8);
      #pragma unroll
      for(int m = 0; m < 4; m++)
        acc[m][j] = __builtin_amdgcn_mfma_f32_16x16x32_bf16(af[m], bfr, acc[m][j], 0,0,0);
    }
  }
  __syncthreads();   // all ZR reads of Alds complete
  #pragma unroll
  for(int j = 0; j < 4; j++){
    int col256 = w*64 + j*16 + lrow;
    if(col256 < 128){
      float bv = bz[col256];
      #pragma unroll
      for(int m = 0; m < 4; m++){
        #pragma unroll
        for(int rr = 0; rr < 4; rr++){
          int row = m*16 + lk*4 + rr;
          Zl[row][col256] = f2bf(sigm(acc[m][j][rr] + bv));
        }
      }
    } else {
      int col = col256 - 128;
      float bv = br[col];
      #pragma unroll
      for(int m = 0; m < 4; m++){
        #pragma unroll
        for(int rr = 0; rr < 4; rr++){
          int row = m*16 + lk*4 + rr;
          int grow = row0 + row;
          if(grow < n){
            float rv = sigm(acc[m][j][rr] + bv);
            float hv = H[(long)grow*DD + col];
            int byte = row*512 + ((2*(128+col)) ^ ((row&7)<<4));
            *(short*)(Alds + byte) = f2bf(rv*hv);
          }
        }
      }
    }
  }
  __syncthreads();   // RH + Z staged
  f32x4 acc2[4][2];
  #pragma unroll
  for(int m = 0; m < 4; m++) for(int j = 0; j < 2; j++) acc2[m][j] = (f32x4){0,0,0,0};
  #pragma unroll
  for(int ks = 0; ks < 8; ks++){
    bf16x8 af[4];
    #pragma unroll
    for(int m = 0; m < 4; m++){
      int r = m*16 + lrow;
      int byte = r*512 + ((ks*64 + lk*16) ^ ((r&7)<<4));
      af[m] = *(const bf16x8*)(Alds + byte);
    }
    #pragma unroll
    for(int j = 0; j < 2; j++){
      int col = w*32 + j*16 + lrow;
      bf16x8 bfr = *(const bf16x8*)(wth + (long)col*256 + ks*32 + lk*8);
      #pragma unroll
      for(int m = 0; m < 4; m++)
        acc2[m][j] = __builtin_amdgcn_mfma_f32_16x16x32_bf16(af[m], bfr, acc2[m][j], 0,0,0);
    }
  }
  #pragma unroll
  for(int j = 0; j < 2; j++){
    int col = w*32 + j*16 + lrow;
    float bv = bh[col];
    #pragma unroll
    for(int m = 0; m < 4; m++){
      #pragma unroll
      for(int rr = 0; rr < 4; rr++){
        int row = m*16 + lk*4 + rr;
        int grow = row0 + row;
        if(grow < n){
          float ht = tanh_f(acc2[m][j][rr] + bv);
          float z = bf2f(Zl[row][col]);
          float Hv = H[(long)grow*DD + col];
          out[(long)grow*DD + col] = z*Hv + (1.f - z)*ht;
        }
      }
    }
  }
}

// ---------------- launch ----------------

extern "C" void kernel_launch(void* const* d_in, const int* in_sizes, int n_in,
                              void* d_out, int out_size, void* d_ws, size_t ws_size,
                              hipStream_t stream){
  const float* x     = (const float*)d_in[0];
  const int*   e32   = (const int*)d_in[1];
  const float* H     = (const float*)d_in[2];
  const float* Wg    = (const float*)d_in[3];
  const float* bg    = (const float*)d_in[4];
  const float* gamma = (const float*)d_in[5];
  const float* beta  = (const float*)d_in[6];
  const float* prelu = (const float*)d_in[7];
  const float* Wz    = (const float*)d_in[8];
  const float* bz    = (const float*)d_in[9];
  const float* Wr    = (const float*)d_in[10];
  const float* br    = (const float*)d_in[11];
  const float* Wh    = (const float*)d_in[12];
  const float* bh    = (const float*)d_in[13];
  float* out = (float*)d_out;
  const int n = in_sizes[0] / DD;
  const int e = in_sizes[1] / 2;
  const int nb = (n + CHUNK - 1) / CHUNK;

  char* ws = (char*)d_ws;
  size_t o = 0;
  auto alloc = [&](size_t bytes)->char*{
    char* p = ws + o; o = (o + bytes + 255) & ~(size_t)255; return p;
  };
  int*   deg    = (int*)  alloc(4L*n);
  float* dinv   = (float*)alloc(4L*n);
  int*   flag   = (int*)  alloc(256);
  float* sum    = (float*)alloc(512);
  float* sumsq  = (float*)alloc(512);
  float* scale  = (float*)alloc(512);
  float* shift  = (float*)alloc(512);
  int*   bsum   = (int*)  alloc(4L*nb);
  int*   offs   = (int*)  alloc(4L*n);
  int*   cursor = (int*)  alloc(4L*n);
  int*   srcs   = (int*)  alloc(4L*e);
  short* wtg    = (short*)alloc(128L*128*2);
  short* wtzr   = (short*)alloc(256L*256*2);
  short* wth    = (short*)alloc(128L*256*2);
  short* hraw   = (short*)alloc(2L*n*DD);

  prep0_k<<<(n+255)/256, 256, 0, stream>>>(deg, sum, sumsq, flag, n);
  flag_k<<<(e+255)/256, 256, 0, stream>>>(e32, flag, e);
  deg_k<<<(e+255)/256, 256, 0, stream>>>(e32, flag, deg, e, n);
  dinv_k<<<(n+255)/256, 256, 0, stream>>>(deg, dinv, n);
  cvtw_k<<<(128*128+255)/256, 256, 0, stream>>>(Wg, wtg, 128, 128);
  cvtw_k<<<(256*128+255)/256, 256, 0, stream>>>(Wz, wtzr, 256, 128);
  cvtw_k<<<(256*128+255)/256, 256, 0, stream>>>(Wr, wtzr + 128*256, 256, 128);
  cvtw_k<<<(256*128+255)/256, 256, 0, stream>>>(Wh, wth, 256, 128);
  scanA_k<<<nb, 256, 0, stream>>>(deg, bsum, n);
  scanB_k<<<1, 64, 0, stream>>>(bsum, nb);
  scanC_k<<<nb, 256, 0, stream>>>(deg, bsum, offs, cursor, n);
  fill_k<<<(e+255)/256, 256, 0, stream>>>(e32, flag, cursor, srcs, e, n);
  const int gb = (n + 63)/64;
  gcn_k<<<gb, 256, 0, stream>>>(x, dinv, offs, deg, srcs, wtg, bg, hraw, sum, sumsq, n);
  bnfin_k<<<1, 128, 0, stream>>>(sum, sumsq, gamma, beta, scale, shift, n);
  gru_k<<<gb, 256, 0, stream>>>(hraw, H, wtzr, wth, scale, shift, prelu, bz, br, bh, out, n);
}

// Round 5
// 302.778 us; speedup vs baseline: 4.5777x; 1.1557x over previous
//
#include <hip/hip_runtime.h>
#include <hip/hip_bf16.h>
#include <stdint.h>

#define DD 128
#define CHUNK 1024

typedef short bf16x8 __attribute__((ext_vector_type(8)));
typedef short bf16x4 __attribute__((ext_vector_type(4)));
typedef float f32x4 __attribute__((ext_vector_type(4)));

__device__ __forceinline__ short f2bf(float f){
  union { float f; uint32_t u; } v; v.f = f;
  uint32_t r = v.u + 0x7fffu + ((v.u >> 16) & 1u);
  return (short)(r >> 16);
}
__device__ __forceinline__ float bf2f(short s){
  union { uint32_t u; float f; } v; v.u = ((uint32_t)(uint16_t)s) << 16;
  return v.f;
}
__device__ __forceinline__ float sigm(float x){ return 1.0f/(1.0f + __expf(-x)); }
__device__ __forceinline__ float tanh_f(float x){ return 1.0f - 2.0f/(__expf(2.0f*x) + 1.0f); }

// ---------------- prep kernels ----------------

__global__ void prep0_k(int* deg, float* sum, float* sumsq, int* flag, int n){
  int i = blockIdx.x*256 + threadIdx.x;
  if(i < n) deg[i] = 1;
  if(blockIdx.x == 0){
    int t = threadIdx.x;
    if(t < DD){ sum[t] = 0.f; sumsq[t] = 0.f; }
    if(t == 0) *flag = 0;
  }
}

// Detect edge_index storage: int64 buffers have zero odd int32 words.
__global__ void flag_k(const int* e32, int* flag, int e){
  int i = blockIdx.x*256 + threadIdx.x;
  if(i < e && e32[2*i+1] != 0) *flag = 1;   // benign race: all write 1
}

__device__ __forceinline__ int eidx(const int* e32, int is32, long pos, int n){
  int v = is32 ? e32[pos] : e32[2*pos];
  return v < 0 ? 0 : (v >= n ? n-1 : v);
}

__global__ void deg_k(const int* e32, const int* flag, int* deg, int e, int n){
  int i = blockIdx.x*256 + threadIdx.x;
  if(i >= e) return;
  int is32 = *flag;
  int c = eidx(e32, is32, (long)e + i, n);  // cols = targets
  atomicAdd(&deg[c], 1);
}

__global__ void dinv_k(const int* deg, float* dinv, int n){
  int i = blockIdx.x*256 + threadIdx.x;
  if(i < n) dinv[i] = rsqrtf((float)deg[i]);
}

// Wt[n*K + k] = bf16(W[k*Nout + n])   (transpose + convert)
__global__ void cvtw_k(const float* w, short* wt, int K, int Nout){
  int t = blockIdx.x*256 + threadIdx.x;
  if(t >= K*Nout) return;
  int nn = t / K, k = t - nn*K;
  wt[t] = f2bf(w[k*Nout + nn]);
}

// xs = bf16(x * dinv[row]);  Hb = bf16(H).  One thread per 8 elements.
__global__ __launch_bounds__(256) void cvtxh_k(const float* x, const float* H,
    const float* dinv, short* xs, short* Hb, int n){
  long i = (long)blockIdx.x*256 + threadIdx.x;
  long tot = (long)n*(DD/8);
  if(i >= 2*tot) return;
  bool isH = i >= tot;
  long j = isH ? i - tot : i;
  const float* src = isH ? H : x;
  f32x4 a = *(const f32x4*)(src + j*8);
  f32x4 b = *(const f32x4*)(src + j*8 + 4);
  float sc = isH ? 1.f : dinv[(int)(j >> 4)];
  bf16x8 o;
  #pragma unroll
  for(int c = 0; c < 4; c++){ o[c] = f2bf(a[c]*sc); o[4+c] = f2bf(b[c]*sc); }
  *(bf16x8*)((isH ? Hb : xs) + j*8) = o;
}

// ---------------- CSR build ----------------

__global__ __launch_bounds__(256) void scanA_k(const int* deg, int* bsum, int n){
  __shared__ int ls[256];
  int b = blockIdx.x, t = threadIdx.x;
  int base = b*CHUNK + t*4;
  int s = 0;
  #pragma unroll
  for(int j = 0; j < 4; j++){ int i = base + j; if(i < n) s += deg[i] - 1; }
  ls[t] = s; __syncthreads();
  for(int off = 128; off > 0; off >>= 1){
    if(t < off) ls[t] += ls[t+off];
    __syncthreads();
  }
  if(t == 0) bsum[b] = ls[0];
}

__global__ void scanB_k(int* bsum, int nb){
  if(threadIdx.x == 0){
    int acc = 0;
    for(int i = 0; i < nb; i++){ int v = bsum[i]; bsum[i] = acc; acc += v; }
  }
}

__global__ __launch_bounds__(256) void scanC_k(const int* deg, const int* bsum,
                                               int* off, int* cursor, int n){
  __shared__ int ls[256];
  int b = blockIdx.x, t = threadIdx.x;
  int base = b*CHUNK + t*4;
  int v[4]; int s = 0;
  #pragma unroll
  for(int j = 0; j < 4; j++){ int i = base + j; v[j] = (i < n) ? deg[i]-1 : 0; s += v[j]; }
  ls[t] = s; __syncthreads();
  for(int d = 1; d < 256; d <<= 1){
    int tmp = (t >= d) ? ls[t-d] : 0;
    __syncthreads();
    ls[t] += tmp;
    __syncthreads();
  }
  int run = bsum[b] + ls[t] - s;   // exclusive prefix
  #pragma unroll
  for(int j = 0; j < 4; j++){
    int i = base + j;
    if(i < n){ off[i] = run; cursor[i] = run; run += v[j]; }
  }
}

__global__ void fill_k(const int* e32, const int* flag, int* cursor, int* srcs,
                       int e, int n){
  int i = blockIdx.x*256 + threadIdx.x;
  if(i >= e) return;
  int is32 = *flag;
  int r = eidx(e32, is32, i, n);
  int c = eidx(e32, is32, (long)e + i, n);
  int slot = atomicAdd(&cursor[c], 1);
  srcs[slot] = r;
}

// ---------------- fused GCN: CSR gather (bf16, pre-scaled) -> LDS -> GEMM ----------
// Gather: 16 groups of 16 lanes per block; group owns a full 128-d row
// (8 bf16/lane). Edges in predicated batches of 8; no dependent dinv load
// (xs is pre-scaled by dinv[src]); final *dinv[node] once.

__global__ __launch_bounds__(256) void gcn_k(const short* xs, const float* dinv,
    const int* offs, const int* deg, const int* srcs, const short* wt,
    const float* bias, short* hraw, float* sum, float* sumsq, int n){
  __shared__ char Alds[64*256];  // 64 rows x 128 bf16, XOR-swizzled
  const int t = threadIdx.x;
  const int row0 = blockIdx.x*64;
  const int g = t >> 4, lane16 = t & 15;
  for(int rr = 0; rr < 4; rr++){
    int row = g*4 + rr;
    int node = row0 + row;
    float acc[8] = {0,0,0,0,0,0,0,0};
    if(node < n){
      float di = dinv[node];
      bf16x8 sv = *(const bf16x8*)(xs + (long)node*DD + lane16*8);
      #pragma unroll
      for(int c = 0; c < 8; c++) acc[c] = bf2f(sv[c]);   // self: dinv[node]*x[node]
      int o0 = offs[node], cnt = deg[node] - 1;
      for(int jb = 0; jb < cnt; jb += 8){
        int rux[8]; float wk[8];
        #pragma unroll
        for(int k = 0; k < 8; k++){
          int jj = jb + k;
          bool ok = jj < cnt;
          rux[k] = srcs[o0 + (ok ? jj : cnt-1)];   // clamped: in-bounds (cnt>=1 here)
          wk[k] = ok ? 1.f : 0.f;
        }
        #pragma unroll
        for(int k = 0; k < 8; k++){
          bf16x8 v = *(const bf16x8*)(xs + (long)rux[k]*DD + lane16*8);
          float wkk = wk[k];
          #pragma unroll
          for(int c = 0; c < 8; c++) acc[c] += bf2f(v[c])*wkk;
        }
      }
      #pragma unroll
      for(int c = 0; c < 8; c++) acc[c] *= di;
    }
    bf16x8 o8;
    #pragma unroll
    for(int c = 0; c < 8; c++) o8[c] = f2bf(acc[c]);
    int byte = row*256 + ((lane16*16) ^ ((row&7)<<4));
    *(bf16x8*)(Alds + byte) = o8;
  }
  __syncthreads();
  const int w = t >> 6, ll = t & 63;
  const int lrow = ll & 15, lk = ll >> 4;
  f32x4 acc[4][2];
  #pragma unroll
  for(int m = 0; m < 4; m++) for(int j = 0; j < 2; j++) acc[m][j] = (f32x4){0,0,0,0};
  #pragma unroll
  for(int ks = 0; ks < 4; ks++){
    bf16x8 af[4];
    #pragma unroll
    for(int m = 0; m < 4; m++){
      int r = m*16 + lrow;
      int byte = r*256 + ((ks*64 + lk*16) ^ ((r&7)<<4));
      af[m] = *(const bf16x8*)(Alds + byte);
    }
    #pragma unroll
    for(int j = 0; j < 2; j++){
      int col = (w*2+j)*16 + lrow;
      bf16x8 bfr = *(const bf16x8*)(wt + col*128 + ks*32 + lk*8);
      #pragma unroll
      for(int m = 0; m < 4; m++)
        acc[m][j] = __builtin_amdgcn_mfma_f32_16x16x32_bf16(af[m], bfr, acc[m][j], 0,0,0);
    }
  }
  #pragma unroll
  for(int j = 0; j < 2; j++){
    int col = (w*2+j)*16 + lrow;
    float bv = bias[col];
    float s = 0.f, s2 = 0.f;
    #pragma unroll
    for(int m = 0; m < 4; m++){
      int rb = row0 + m*16 + lk*4;
      #pragma unroll
      for(int rr = 0; rr < 4; rr++){
        int row = rb + rr;
        if(row < n){
          float h = acc[m][j][rr] + bv;
          hraw[(long)row*DD + col] = f2bf(h);
          s += h; s2 += h*h;
        }
      }
    }
    s  += __shfl_xor(s, 16);  s  += __shfl_xor(s, 32);
    s2 += __shfl_xor(s2, 16); s2 += __shfl_xor(s2, 32);
    if(lk == 0){
      atomicAdd(&sum[col], s);
      atomicAdd(&sumsq[col], s2);
    }
  }
}

__global__ void bnfin_k(const float* sum, const float* sumsq, const float* gamma,
                        const float* beta, float* scale, float* shift, int n){
  int c = threadIdx.x;
  if(c >= DD) return;
  float inv_n = 1.0f/(float)n;
  float mean = sum[c]*inv_n;
  float var = sumsq[c]*inv_n - mean*mean;
  float sc = gamma[c]*rsqrtf(var + 1e-5f);
  scale[c] = sc;
  shift[c] = beta[c] - mean*sc;
}

// ---------------- fused GRU (H read as bf16 Hb) ----------------

__global__ __launch_bounds__(256) void gru_k(const short* hraw, const short* Hb,
    const short* wtzr, const short* wth, const float* scale, const float* shift,
    const float* prelu, const float* bz, const float* br, const float* bh,
    float* out, int n){
  __shared__ char Alds[64*512];     // [64][256] bf16, XOR-swizzled: [h_act | H] -> [h_act | R*H]
  __shared__ short Zl[64][136];     // Z bf16, +8 pad
  const int t = threadIdx.x;
  const int row0 = blockIdx.x*64;
  const float pa = prelu[0];
  for(int u = t; u < 2048; u += 256){
    int r = u >> 5, ku = u & 31;
    int grow = row0 + r;
    bf16x8 wv = {0,0,0,0,0,0,0,0};
    if(ku < 16){
      if(grow < n){
        bf16x8 hv = *(const bf16x8*)(hraw + (long)grow*DD + ku*8);
        #pragma unroll
        for(int j = 0; j < 8; j++){
          int c = ku*8 + j;
          float f = bf2f(hv[j])*scale[c] + shift[c];
          f = f > 0.f ? f : pa*f;
          wv[j] = f2bf(f);
        }
      }
    } else {
      if(grow < n) wv = *(const bf16x8*)(Hb + (long)grow*DD + (ku-16)*8);
    }
    int byte = r*512 + ((ku*16) ^ ((r&7)<<4));
    *(bf16x8*)(Alds + byte) = wv;
  }
  __syncthreads();
  const int w = t >> 6, l = t & 63;
  const int lrow = l & 15, lk = l >> 4;
  f32x4 acc[4][4];
  #pragma unroll
  for(int m = 0; m < 4; m++) for(int j = 0; j < 4; j++) acc[m][j] = (f32x4){0,0,0,0};
  #pragma unroll
  for(int ks = 0; ks < 8; ks++){
    bf16x8 af[4];
    #pragma unroll
    for(int m = 0; m < 4; m++){
      int r = m*16 + lrow;
      int byte = r*512 + ((ks*64 + lk*16) ^ ((r&7)<<4));
      af[m] = *(const bf16x8*)(Alds + byte);
    }
    #pragma unroll
    for(int j = 0; j < 4; j++){
      int col = w*64 + j*16 + lrow;
      bf16x8 bfr = *(const bf16x8*)(wtzr + (long)col*256 + ks*32 + lk*8);
      #pragma unroll
      for(int m = 0; m < 4; m++)
        acc[m][j] = __builtin_amdgcn_mfma_f32_16x16x32_bf16(af[m], bfr, acc[m][j], 0,0,0);
    }
  }
  __syncthreads();   // all ZR reads of Alds complete
  #pragma unroll
  for(int j = 0; j < 4; j++){
    int col256 = w*64 + j*16 + lrow;
    if(col256 < 128){
      float bv = bz[col256];
      #pragma unroll
      for(int m = 0; m < 4; m++){
        #pragma unroll
        for(int rr = 0; rr < 4; rr++){
          int row = m*16 + lk*4 + rr;
          Zl[row][col256] = f2bf(sigm(acc[m][j][rr] + bv));
        }
      }
    } else {
      int col = col256 - 128;
      float bv = br[col];
      #pragma unroll
      for(int m = 0; m < 4; m++){
        #pragma unroll
        for(int rr = 0; rr < 4; rr++){
          int row = m*16 + lk*4 + rr;
          int grow = row0 + row;
          if(grow < n){
            float rv = sigm(acc[m][j][rr] + bv);
            float hv = bf2f(Hb[(long)grow*DD + col]);
            int byte = row*512 + ((2*(128+col)) ^ ((row&7)<<4));
            *(short*)(Alds + byte) = f2bf(rv*hv);
          }
        }
      }
    }
  }
  __syncthreads();   // RH + Z staged
  f32x4 acc2[4][2];
  #pragma unroll
  for(int m = 0; m < 4; m++) for(int j = 0; j < 2; j++) acc2[m][j] = (f32x4){0,0,0,0};
  #pragma unroll
  for(int ks = 0; ks < 8; ks++){
    bf16x8 af[4];
    #pragma unroll
    for(int m = 0; m < 4; m++){
      int r = m*16 + lrow;
      int byte = r*512 + ((ks*64 + lk*16) ^ ((r&7)<<4));
      af[m] = *(const bf16x8*)(Alds + byte);
    }
    #pragma unroll
    for(int j = 0; j < 2; j++){
      int col = w*32 + j*16 + lrow;
      bf16x8 bfr = *(const bf16x8*)(wth + (long)col*256 + ks*32 + lk*8);
      #pragma unroll
      for(int m = 0; m < 4; m++)
        acc2[m][j] = __builtin_amdgcn_mfma_f32_16x16x32_bf16(af[m], bfr, acc2[m][j], 0,0,0);
    }
  }
  #pragma unroll
  for(int j = 0; j < 2; j++){
    int col = w*32 + j*16 + lrow;
    float bv = bh[col];
    #pragma unroll
    for(int m = 0; m < 4; m++){
      #pragma unroll
      for(int rr = 0; rr < 4; rr++){
        int row = m*16 + lk*4 + rr;
        int grow = row0 + row;
        if(grow < n){
          float ht = tanh_f(acc2[m][j][rr] + bv);
          float z = bf2f(Zl[row][col]);
          float Hv = bf2f(Hb[(long)grow*DD + col]);
          out[(long)grow*DD + col] = z*Hv + (1.f - z)*ht;
        }
      }
    }
  }
}

// ---------------- launch ----------------

extern "C" void kernel_launch(void* const* d_in, const int* in_sizes, int n_in,
                              void* d_out, int out_size, void* d_ws, size_t ws_size,
                              hipStream_t stream){
  const float* x     = (const float*)d_in[0];
  const int*   e32   = (const int*)d_in[1];
  const float* H     = (const float*)d_in[2];
  const float* Wg    = (const float*)d_in[3];
  const float* bg    = (const float*)d_in[4];
  const float* gamma = (const float*)d_in[5];
  const float* beta  = (const float*)d_in[6];
  const float* prelu = (const float*)d_in[7];
  const float* Wz    = (const float*)d_in[8];
  const float* bz    = (const float*)d_in[9];
  const float* Wr    = (const float*)d_in[10];
  const float* br    = (const float*)d_in[11];
  const float* Wh    = (const float*)d_in[12];
  const float* bh    = (const float*)d_in[13];
  float* out = (float*)d_out;
  const int n = in_sizes[0] / DD;
  const int e = in_sizes[1] / 2;
  const int nb = (n + CHUNK - 1) / CHUNK;

  char* ws = (char*)d_ws;
  size_t o = 0;
  auto alloc = [&](size_t bytes)->char*{
    char* p = ws + o; o = (o + bytes + 255) & ~(size_t)255; return p;
  };
  int*   deg    = (int*)  alloc(4L*n);
  float* dinv   = (float*)alloc(4L*n);
  int*   flag   = (int*)  alloc(256);
  float* sum    = (float*)alloc(512);
  float* sumsq  = (float*)alloc(512);
  float* scale  = (float*)alloc(512);
  float* shift  = (float*)alloc(512);
  int*   bsum   = (int*)  alloc(4L*nb);
  int*   offs   = (int*)  alloc(4L*n);
  int*   cursor = (int*)  alloc(4L*n);
  int*   srcs   = (int*)  alloc(4L*e);
  short* wtg    = (short*)alloc(128L*128*2);
  short* wtzr   = (short*)alloc(256L*256*2);
  short* wth    = (short*)alloc(128L*256*2);
  short* hraw   = (short*)alloc(2L*n*DD);
  short* xs     = (short*)alloc(2L*n*DD);
  short* Hb     = (short*)alloc(2L*n*DD);

  prep0_k<<<(n+255)/256, 256, 0, stream>>>(deg, sum, sumsq, flag, n);
  flag_k<<<(e+255)/256, 256, 0, stream>>>(e32, flag, e);
  deg_k<<<(e+255)/256, 256, 0, stream>>>(e32, flag, deg, e, n);
  dinv_k<<<(n+255)/256, 256, 0, stream>>>(deg, dinv, n);
  cvtw_k<<<(128*128+255)/256, 256, 0, stream>>>(Wg, wtg, 128, 128);
  cvtw_k<<<(256*128+255)/256, 256, 0, stream>>>(Wz, wtzr, 256, 128);
  cvtw_k<<<(256*128+255)/256, 256, 0, stream>>>(Wr, wtzr + 128*256, 256, 128);
  cvtw_k<<<(256*128+255)/256, 256, 0, stream>>>(Wh, wth, 256, 128);
  {
    long blocks = (2L*n*(DD/8) + 255) / 256;
    cvtxh_k<<<(int)blocks, 256, 0, stream>>>(x, H, dinv, xs, Hb, n);
  }
  scanA_k<<<nb, 256, 0, stream>>>(deg, bsum, n);
  scanB_k<<<1, 64, 0, stream>>>(bsum, nb);
  scanC_k<<<nb, 256, 0, stream>>>(deg, bsum, offs, cursor, n);
  fill_k<<<(e+255)/256, 256, 0, stream>>>(e32, flag, cursor, srcs, e, n);
  const int gb = (n + 63)/64;
  gcn_k<<<gb, 256, 0, stream>>>(xs, dinv, offs, deg, srcs, wtg, bg, hraw, sum, sumsq, n);
  bnfin_k<<<1, 128, 0, stream>>>(sum, sumsq, gamma, beta, scale, shift, n);
  gru_k<<<gb, 256, 0, stream>>>(hraw, Hb, wtzr, wth, scale, shift, prelu, bz, br, bh, out, n);
}

// Round 6
// 276.123 us; speedup vs baseline: 5.0196x; 1.0965x over previous
//
#include <hip/hip_runtime.h>
#include <hip/hip_bf16.h>
#include <stdint.h>

#define DD 128
#define CHUNK 1024

typedef short bf16x8 __attribute__((ext_vector_type(8)));
typedef short bf16x4 __attribute__((ext_vector_type(4)));
typedef float f32x4 __attribute__((ext_vector_type(4)));

__device__ __forceinline__ short f2bf(float f){
  union { float f; uint32_t u; } v; v.f = f;
  uint32_t r = v.u + 0x7fffu + ((v.u >> 16) & 1u);
  return (short)(r >> 16);
}
__device__ __forceinline__ float bf2f(short s){
  union { uint32_t u; float f; } v; v.u = ((uint32_t)(uint16_t)s) << 16;
  return v.f;
}
__device__ __forceinline__ float sigm(float x){ return 1.0f/(1.0f + __expf(-x)); }
__device__ __forceinline__ float tanh_f(float x){ return 1.0f - 2.0f/(__expf(2.0f*x) + 1.0f); }

// ---------------- init: deg=1, edge-dtype detect, all weight transposes ----------------
// flag/sum/sumsq are pre-zeroed by hipMemsetAsync before this kernel.

__global__ __launch_bounds__(256) void init_k(int* deg, const int* e32, int* flag,
    const float* Wg, const float* Wz, const float* Wr, const float* Wh,
    short* wtg, short* wtzr, short* wth, int n, int e){
  int i = blockIdx.x*256 + threadIdx.x;
  if(i < n) deg[i] = 1;                       // self loop
  if(i < e && e32[2*i+1] != 0) *flag = 1;     // int32 storage detected (benign race)
  if(i < 16384){
    int nn = i >> 7, k = i & 127;
    wtg[i] = f2bf(Wg[k*128 + nn]);
  } else if(i < 49152){
    int j = i - 16384; int nn = j >> 8, k = j & 255;
    wtzr[nn*256 + k] = f2bf(Wz[k*128 + nn]);
  } else if(i < 81920){
    int j = i - 49152; int nn = j >> 8, k = j & 255;
    wtzr[(128+nn)*256 + k] = f2bf(Wr[k*128 + nn]);
  } else if(i < 114688){
    int j = i - 81920; int nn = j >> 8, k = j & 255;
    wth[nn*256 + k] = f2bf(Wh[k*128 + nn]);
  }
}

__device__ __forceinline__ int eidx(const int* e32, int is32, long pos, int n){
  int v = is32 ? e32[pos] : e32[2*pos];
  return v < 0 ? 0 : (v >= n ? n-1 : v);
}

__global__ void deg_k(const int* e32, const int* flag, int* deg, int e, int n){
  int i = blockIdx.x*256 + threadIdx.x;
  if(i >= e) return;
  int is32 = *flag;
  int c = eidx(e32, is32, (long)e + i, n);  // cols = targets
  atomicAdd(&deg[c], 1);
}

// ---------------- scanA (per-chunk sums) + dinv, merged ----------------

__global__ __launch_bounds__(256) void dscanA_k(const int* deg, int* bsum,
                                                float* dinv, int n, int nb){
  int t = threadIdx.x;
  if((int)blockIdx.x < nb){
    __shared__ int ls[256];
    int b = blockIdx.x;
    int base = b*CHUNK + t*4;
    int s = 0;
    #pragma unroll
    for(int j = 0; j < 4; j++){ int i = base + j; if(i < n) s += deg[i] - 1; }
    ls[t] = s; __syncthreads();
    for(int off = 128; off > 0; off >>= 1){
      if(t < off) ls[t] += ls[t+off];
      __syncthreads();
    }
    if(t == 0) bsum[b] = ls[0];
  } else {
    int i = (blockIdx.x - nb)*256 + t;
    if(i < n) dinv[i] = rsqrtf((float)deg[i]);
  }
}

// ---------------- scanB (parallel exclusive scan of bsum) + cvtxh, merged ----------

__global__ __launch_bounds__(256) void scanBcvt_k(int* bsum, int nb,
    const float* x, const float* H, const float* dinv, short* xs, short* Hb, int n){
  int t = threadIdx.x;
  if(blockIdx.x == 0){
    if(nb <= 256){
      __shared__ int ls[256];
      int v = (t < nb) ? bsum[t] : 0;
      ls[t] = v; __syncthreads();
      for(int d = 1; d < 256; d <<= 1){
        int tmp = (t >= d) ? ls[t-d] : 0;
        __syncthreads();
        ls[t] += tmp;
        __syncthreads();
      }
      if(t < nb) bsum[t] = ls[t] - v;   // exclusive
    } else if(t == 0){
      int acc = 0;
      for(int i = 0; i < nb; i++){ int v = bsum[i]; bsum[i] = acc; acc += v; }
    }
  } else {
    long i = (long)(blockIdx.x - 1)*256 + t;
    long tot = (long)n*(DD/8);
    if(i >= 2*tot) return;
    bool isH = i >= tot;
    long j = isH ? i - tot : i;
    const float* src = isH ? H : x;
    f32x4 a = *(const f32x4*)(src + j*8);
    f32x4 b = *(const f32x4*)(src + j*8 + 4);
    float sc = isH ? 1.f : dinv[(int)(j >> 4)];
    bf16x8 o;
    #pragma unroll
    for(int c = 0; c < 4; c++){ o[c] = f2bf(a[c]*sc); o[4+c] = f2bf(b[c]*sc); }
    *(bf16x8*)((isH ? Hb : xs) + j*8) = o;
  }
}

__global__ __launch_bounds__(256) void scanC_k(const int* deg, const int* bsum,
                                               int* off, int* cursor, int n){
  __shared__ int ls[256];
  int b = blockIdx.x, t = threadIdx.x;
  int base = b*CHUNK + t*4;
  int v[4]; int s = 0;
  #pragma unroll
  for(int j = 0; j < 4; j++){ int i = base + j; v[j] = (i < n) ? deg[i]-1 : 0; s += v[j]; }
  ls[t] = s; __syncthreads();
  for(int d = 1; d < 256; d <<= 1){
    int tmp = (t >= d) ? ls[t-d] : 0;
    __syncthreads();
    ls[t] += tmp;
    __syncthreads();
  }
  int run = bsum[b] + ls[t] - s;   // exclusive prefix
  #pragma unroll
  for(int j = 0; j < 4; j++){
    int i = base + j;
    if(i < n){ off[i] = run; cursor[i] = run; run += v[j]; }
  }
}

__global__ void fill_k(const int* e32, const int* flag, int* cursor, int* srcs,
                       int e, int n){
  int i = blockIdx.x*256 + threadIdx.x;
  if(i >= e) return;
  int is32 = *flag;
  int r = eidx(e32, is32, i, n);
  int c = eidx(e32, is32, (long)e + i, n);
  int slot = atomicAdd(&cursor[c], 1);
  srcs[slot] = r;
}

// ---------------- fused GCN: CSR gather (bf16, pre-scaled) -> LDS -> GEMM ----------

__global__ __launch_bounds__(256) void gcn_k(const short* xs, const float* dinv,
    const int* offs, const int* deg, const int* srcs, const short* wt,
    const float* bias, short* hraw, float* sum, float* sumsq, int n){
  __shared__ char Alds[64*256];  // 64 rows x 128 bf16, XOR-swizzled
  const int t = threadIdx.x;
  const int row0 = blockIdx.x*64;
  const int g = t >> 4, lane16 = t & 15;
  for(int rr = 0; rr < 4; rr++){
    int row = g*4 + rr;
    int node = row0 + row;
    float acc[8] = {0,0,0,0,0,0,0,0};
    if(node < n){
      float di = dinv[node];
      bf16x8 sv = *(const bf16x8*)(xs + (long)node*DD + lane16*8);
      #pragma unroll
      for(int c = 0; c < 8; c++) acc[c] = bf2f(sv[c]);   // self: dinv[node]*x[node]
      int o0 = offs[node], cnt = deg[node] - 1;
      for(int jb = 0; jb < cnt; jb += 8){
        int rux[8]; float wk[8];
        #pragma unroll
        for(int k = 0; k < 8; k++){
          int jj = jb + k;
          bool ok = jj < cnt;
          rux[k] = srcs[o0 + (ok ? jj : cnt-1)];
          wk[k] = ok ? 1.f : 0.f;
        }
        #pragma unroll
        for(int k = 0; k < 8; k++){
          bf16x8 v = *(const bf16x8*)(xs + (long)rux[k]*DD + lane16*8);
          float wkk = wk[k];
          #pragma unroll
          for(int c = 0; c < 8; c++) acc[c] += bf2f(v[c])*wkk;
        }
      }
      #pragma unroll
      for(int c = 0; c < 8; c++) acc[c] *= di;
    }
    bf16x8 o8;
    #pragma unroll
    for(int c = 0; c < 8; c++) o8[c] = f2bf(acc[c]);
    int byte = row*256 + ((lane16*16) ^ ((row&7)<<4));
    *(bf16x8*)(Alds + byte) = o8;
  }
  __syncthreads();
  const int w = t >> 6, ll = t & 63;
  const int lrow = ll & 15, lk = ll >> 4;
  f32x4 acc[4][2];
  #pragma unroll
  for(int m = 0; m < 4; m++) for(int j = 0; j < 2; j++) acc[m][j] = (f32x4){0,0,0,0};
  #pragma unroll
  for(int ks = 0; ks < 4; ks++){
    bf16x8 af[4];
    #pragma unroll
    for(int m = 0; m < 4; m++){
      int r = m*16 + lrow;
      int byte = r*256 + ((ks*64 + lk*16) ^ ((r&7)<<4));
      af[m] = *(const bf16x8*)(Alds + byte);
    }
    #pragma unroll
    for(int j = 0; j < 2; j++){
      int col = (w*2+j)*16 + lrow;
      bf16x8 bfr = *(const bf16x8*)(wt + col*128 + ks*32 + lk*8);
      #pragma unroll
      for(int m = 0; m < 4; m++)
        acc[m][j] = __builtin_amdgcn_mfma_f32_16x16x32_bf16(af[m], bfr, acc[m][j], 0,0,0);
    }
  }
  #pragma unroll
  for(int j = 0; j < 2; j++){
    int col = (w*2+j)*16 + lrow;
    float bv = bias[col];
    float s = 0.f, s2 = 0.f;
    #pragma unroll
    for(int m = 0; m < 4; m++){
      int rb = row0 + m*16 + lk*4;
      #pragma unroll
      for(int rr = 0; rr < 4; rr++){
        int row = rb + rr;
        if(row < n){
          float h = acc[m][j][rr] + bv;
          hraw[(long)row*DD + col] = f2bf(h);
          s += h; s2 += h*h;
        }
      }
    }
    s  += __shfl_xor(s, 16);  s  += __shfl_xor(s, 32);
    s2 += __shfl_xor(s2, 16); s2 += __shfl_xor(s2, 32);
    if(lk == 0){
      atomicAdd(&sum[col], s);
      atomicAdd(&sumsq[col], s2);
    }
  }
}

// ---------------- fused GRU: M=32 tile, BN inline, RH from LDS ----------------
// LDS ~26KB -> 6 blocks/CU. ZR GEMM: wave w owns cols [64w,64w+64), m 0-1.
// HT GEMM: wave w owns cols [32w,32w+32), m 0-1.

__global__ __launch_bounds__(256) void gru_k(const short* hraw, const short* Hb,
    const short* wtzr, const short* wth, const float* sum, const float* sumsq,
    const float* gamma, const float* beta, const float* prelu,
    const float* bz, const float* br, const float* bh, float* out, int n){
  __shared__ char Alds[32*512];     // [32][256] bf16, XOR-swizzled: [h_act | H] -> [h_act | R*H]
  __shared__ short Zl[32][132];     // Z bf16, stride 132 (bank-clean for lk-groups)
  __shared__ float sSc[128], sSh[128];
  const int t = threadIdx.x;
  const int row0 = blockIdx.x*32;
  const float pa = prelu[0];
  if(t < 128){
    float inv_n = 1.0f/(float)n;
    float mean = sum[t]*inv_n;
    float var = sumsq[t]*inv_n - mean*mean;
    float sc = gamma[t]*rsqrtf(var + 1e-5f);
    sSc[t] = sc; sSh[t] = beta[t] - mean*sc;
  }
  __syncthreads();
  for(int u = t; u < 1024; u += 256){
    int r = u >> 5, ku = u & 31;
    int grow = row0 + r;
    bf16x8 wv = {0,0,0,0,0,0,0,0};
    if(ku < 16){
      if(grow < n){
        bf16x8 hv = *(const bf16x8*)(hraw + (long)grow*DD + ku*8);
        #pragma unroll
        for(int j = 0; j < 8; j++){
          int c = ku*8 + j;
          float f = bf2f(hv[j])*sSc[c] + sSh[c];
          f = f > 0.f ? f : pa*f;
          wv[j] = f2bf(f);
        }
      }
    } else {
      if(grow < n) wv = *(const bf16x8*)(Hb + (long)grow*DD + (ku-16)*8);
    }
    int byte = r*512 + ((ku*16) ^ ((r&7)<<4));
    *(bf16x8*)(Alds + byte) = wv;
  }
  __syncthreads();
  const int w = t >> 6, l = t & 63;
  const int lrow = l & 15, lk = l >> 4;
  f32x4 acc[2][4];
  #pragma unroll
  for(int m = 0; m < 2; m++) for(int j = 0; j < 4; j++) acc[m][j] = (f32x4){0,0,0,0};
  #pragma unroll
  for(int ks = 0; ks < 8; ks++){
    bf16x8 af[2];
    #pragma unroll
    for(int m = 0; m < 2; m++){
      int r = m*16 + lrow;
      int byte = r*512 + ((ks*64 + lk*16) ^ ((r&7)<<4));
      af[m] = *(const bf16x8*)(Alds + byte);
    }
    #pragma unroll
    for(int j = 0; j < 4; j++){
      int col = w*64 + j*16 + lrow;
      bf16x8 bfr = *(const bf16x8*)(wtzr + (long)col*256 + ks*32 + lk*8);
      #pragma unroll
      for(int m = 0; m < 2; m++)
        acc[m][j] = __builtin_amdgcn_mfma_f32_16x16x32_bf16(af[m], bfr, acc[m][j], 0,0,0);
    }
  }
  __syncthreads();   // all ZR reads of Alds complete
  #pragma unroll
  for(int j = 0; j < 4; j++){
    int col256 = w*64 + j*16 + lrow;
    if(col256 < 128){
      float bv = bz[col256];
      #pragma unroll
      for(int m = 0; m < 2; m++){
        #pragma unroll
        for(int rr = 0; rr < 4; rr++){
          int row = m*16 + lk*4 + rr;
          Zl[row][col256] = f2bf(sigm(acc[m][j][rr] + bv));
        }
      }
    } else {
      float bv = br[col256 - 128];
      #pragma unroll
      for(int m = 0; m < 2; m++){
        #pragma unroll
        for(int rr = 0; rr < 4; rr++){
          int row = m*16 + lk*4 + rr;
          float rv = sigm(acc[m][j][rr] + bv);
          int byte = row*512 + ((2*col256) ^ ((row&7)<<4));
          short hv16 = *(short*)(Alds + byte);          // staged H (bf16)
          *(short*)(Alds + byte) = f2bf(rv*bf2f(hv16)); // overwrite with R*H
        }
      }
    }
  }
  __syncthreads();   // RH + Z staged
  f32x4 acc2[2][2];
  #pragma unroll
  for(int m = 0; m < 2; m++) for(int j = 0; j < 2; j++) acc2[m][j] = (f32x4){0,0,0,0};
  #pragma unroll
  for(int ks = 0; ks < 8; ks++){
    bf16x8 af[2];
    #pragma unroll
    for(int m = 0; m < 2; m++){
      int r = m*16 + lrow;
      int byte = r*512 + ((ks*64 + lk*16) ^ ((r&7)<<4));
      af[m] = *(const bf16x8*)(Alds + byte);
    }
    #pragma unroll
    for(int j = 0; j < 2; j++){
      int col = w*32 + j*16 + lrow;
      bf16x8 bfr = *(const bf16x8*)(wth + (long)col*256 + ks*32 + lk*8);
      #pragma unroll
      for(int m = 0; m < 2; m++)
        acc2[m][j] = __builtin_amdgcn_mfma_f32_16x16x32_bf16(af[m], bfr, acc2[m][j], 0,0,0);
    }
  }
  #pragma unroll
  for(int j = 0; j < 2; j++){
    int col = w*32 + j*16 + lrow;
    float bv = bh[col];
    #pragma unroll
    for(int m = 0; m < 2; m++){
      #pragma unroll
      for(int rr = 0; rr < 4; rr++){
        int row = m*16 + lk*4 + rr;
        int grow = row0 + row;
        if(grow < n){
          float ht = tanh_f(acc2[m][j][rr] + bv);
          float z = bf2f(Zl[row][col]);
          float Hv = bf2f(Hb[(long)grow*DD + col]);
          out[(long)grow*DD + col] = z*Hv + (1.f - z)*ht;
        }
      }
    }
  }
}

// ---------------- launch ----------------

extern "C" void kernel_launch(void* const* d_in, const int* in_sizes, int n_in,
                              void* d_out, int out_size, void* d_ws, size_t ws_size,
                              hipStream_t stream){
  const float* x     = (const float*)d_in[0];
  const int*   e32   = (const int*)d_in[1];
  const float* H     = (const float*)d_in[2];
  const float* Wg    = (const float*)d_in[3];
  const float* bg    = (const float*)d_in[4];
  const float* gamma = (const float*)d_in[5];
  const float* beta  = (const float*)d_in[6];
  const float* prelu = (const float*)d_in[7];
  const float* Wz    = (const float*)d_in[8];
  const float* bz    = (const float*)d_in[9];
  const float* Wr    = (const float*)d_in[10];
  const float* br    = (const float*)d_in[11];
  const float* Wh    = (const float*)d_in[12];
  const float* bh    = (const float*)d_in[13];
  float* out = (float*)d_out;
  const int n = in_sizes[0] / DD;
  const int e = in_sizes[1] / 2;
  const int nb = (n + CHUNK - 1) / CHUNK;

  char* ws = (char*)d_ws;
  size_t o = 0;
  auto alloc = [&](size_t bytes)->char*{
    char* p = ws + o; o = (o + bytes + 255) & ~(size_t)255; return p;
  };
  int*   deg    = (int*)  alloc(4L*n);
  float* dinv   = (float*)alloc(4L*n);
  int*   flag   = (int*)  alloc(256);   // flag+sum+sumsq contiguous: one memset
  float* sum    = (float*)alloc(512);
  float* sumsq  = (float*)alloc(512);
  int*   bsum   = (int*)  alloc(4L*nb);
  int*   offs   = (int*)  alloc(4L*n);
  int*   cursor = (int*)  alloc(4L*n);
  int*   srcs   = (int*)  alloc(4L*e);
  short* wtg    = (short*)alloc(128L*128*2);
  short* wtzr   = (short*)alloc(256L*256*2);
  short* wth    = (short*)alloc(128L*256*2);
  short* hraw   = (short*)alloc(2L*n*DD);
  short* xs     = (short*)alloc(2L*n*DD);
  short* Hb     = (short*)alloc(2L*n*DD);

  hipMemsetAsync(flag, 0, 1280, stream);   // flag + sum + sumsq

  int gi = (n + 255)/256;
  int ge = (e + 255)/256;
  int ginit = gi > ge ? gi : ge;
  if(ginit < 448) ginit = 448;             // cover 114688 weight elements
  init_k<<<ginit, 256, 0, stream>>>(deg, e32, flag, Wg, Wz, Wr, Wh, wtg, wtzr, wth, n, e);
  deg_k<<<ge, 256, 0, stream>>>(e32, flag, deg, e, n);
  dscanA_k<<<nb + gi, 256, 0, stream>>>(deg, bsum, dinv, n, nb);
  {
    int cvb = (int)((2L*n*(DD/8) + 255) / 256);
    scanBcvt_k<<<1 + cvb, 256, 0, stream>>>(bsum, nb, x, H, dinv, xs, Hb, n);
  }
  scanC_k<<<nb, 256, 0, stream>>>(deg, bsum, offs, cursor, n);
  fill_k<<<ge, 256, 0, stream>>>(e32, flag, cursor, srcs, e, n);
  gcn_k<<<(n + 63)/64, 256, 0, stream>>>(xs, dinv, offs, deg, srcs, wtg, bg, hraw, sum, sumsq, n);
  gru_k<<<(n + 31)/32, 256, 0, stream>>>(hraw, Hb, wtzr, wth, sum, sumsq, gamma, beta, prelu, bz, br, bh, out, n);
}

// Round 7
// 271.626 us; speedup vs baseline: 5.1027x; 1.0166x over previous
//
#include <hip/hip_runtime.h>
#include <hip/hip_bf16.h>
#include <stdint.h>

#define DD 128
#define CHUNK 1024

typedef short bf16x8 __attribute__((ext_vector_type(8)));
typedef short bf16x4 __attribute__((ext_vector_type(4)));
typedef float f32x4 __attribute__((ext_vector_type(4)));
typedef uint32_t u32x4 __attribute__((ext_vector_type(4)));

__device__ __forceinline__ short f2bf(float f){
  union { float f; uint32_t u; } v; v.f = f;
  uint32_t r = v.u + 0x7fffu + ((v.u >> 16) & 1u);
  return (short)(r >> 16);
}
__device__ __forceinline__ float bf2f(short s){
  union { uint32_t u; float f; } v; v.u = ((uint32_t)(uint16_t)s) << 16;
  return v.f;
}
// packed bf16 convert: lo = bf16(a), hi = bf16(b)  (RNE, hardware)
__device__ __forceinline__ uint32_t cvt_pk_bf16(float a, float b){
  uint32_t r;
  asm("v_cvt_pk_bf16_f32 %0, %1, %2" : "=v"(r) : "v"(a), "v"(b));
  return r;
}
__device__ __forceinline__ float sigm(float x){ return 1.0f/(1.0f + __expf(-x)); }
__device__ __forceinline__ float tanh_f(float x){ return 1.0f - 2.0f/(__expf(2.0f*x) + 1.0f); }

// ---------------- init: deg=1, edge-dtype detect, all weight transposes ----------------
// flag/sum/sumsq are pre-zeroed by hipMemsetAsync before this kernel.

__global__ __launch_bounds__(256) void init_k(int* deg, const int* e32, int* flag,
    const float* Wg, const float* Wz, const float* Wr, const float* Wh,
    short* wtg, short* wtzr, short* wth, int n, int e){
  int i = blockIdx.x*256 + threadIdx.x;
  if(i < n) deg[i] = 1;                       // self loop
  if(i < e && e32[2*i+1] != 0) *flag = 1;     // int32 storage detected (benign race)
  if(i < 16384){
    int nn = i >> 7, k = i & 127;
    wtg[i] = f2bf(Wg[k*128 + nn]);
  } else if(i < 49152){
    int j = i - 16384; int nn = j >> 8, k = j & 255;
    wtzr[nn*256 + k] = f2bf(Wz[k*128 + nn]);
  } else if(i < 81920){
    int j = i - 49152; int nn = j >> 8, k = j & 255;
    wtzr[(128+nn)*256 + k] = f2bf(Wr[k*128 + nn]);
  } else if(i < 114688){
    int j = i - 81920; int nn = j >> 8, k = j & 255;
    wth[nn*256 + k] = f2bf(Wh[k*128 + nn]);
  }
}

__device__ __forceinline__ int eidx(const int* e32, int is32, long pos, int n){
  int v = is32 ? e32[pos] : e32[2*pos];
  return v < 0 ? 0 : (v >= n ? n-1 : v);
}

__global__ void deg_k(const int* e32, const int* flag, int* deg, int e, int n){
  int i = blockIdx.x*256 + threadIdx.x;
  if(i >= e) return;
  int is32 = *flag;
  int c = eidx(e32, is32, (long)e + i, n);  // cols = targets
  atomicAdd(&deg[c], 1);
}

// ---------------- scanA (per-chunk sums) + dinv, merged ----------------

__global__ __launch_bounds__(256) void dscanA_k(const int* deg, int* bsum,
                                                float* dinv, int n, int nb){
  int t = threadIdx.x;
  if((int)blockIdx.x < nb){
    __shared__ int ls[256];
    int b = blockIdx.x;
    int base = b*CHUNK + t*4;
    int s = 0;
    #pragma unroll
    for(int j = 0; j < 4; j++){ int i = base + j; if(i < n) s += deg[i] - 1; }
    ls[t] = s; __syncthreads();
    for(int off = 128; off > 0; off >>= 1){
      if(t < off) ls[t] += ls[t+off];
      __syncthreads();
    }
    if(t == 0) bsum[b] = ls[0];
  } else {
    int i = (blockIdx.x - nb)*256 + t;
    if(i < n) dinv[i] = rsqrtf((float)deg[i]);
  }
}

// ---------------- scanB (parallel exclusive scan of bsum) + cvtxh, merged ----------

__global__ __launch_bounds__(256) void scanBcvt_k(int* bsum, int nb,
    const float* x, const float* H, const float* dinv, short* xs, short* Hb, int n){
  int t = threadIdx.x;
  if(blockIdx.x == 0){
    if(nb <= 256){
      __shared__ int ls[256];
      int v = (t < nb) ? bsum[t] : 0;
      ls[t] = v; __syncthreads();
      for(int d = 1; d < 256; d <<= 1){
        int tmp = (t >= d) ? ls[t-d] : 0;
        __syncthreads();
        ls[t] += tmp;
        __syncthreads();
      }
      if(t < nb) bsum[t] = ls[t] - v;   // exclusive
    } else if(t == 0){
      int acc = 0;
      for(int i = 0; i < nb; i++){ int v = bsum[i]; bsum[i] = acc; acc += v; }
    }
  } else {
    long i = (long)(blockIdx.x - 1)*256 + t;
    long tot = (long)n*(DD/8);
    if(i >= 2*tot) return;
    bool isH = i >= tot;
    long j = isH ? i - tot : i;
    const float* src = isH ? H : x;
    f32x4 a = *(const f32x4*)(src + j*8);
    f32x4 b = *(const f32x4*)(src + j*8 + 4);
    float sc = isH ? 1.f : dinv[(int)(j >> 4)];
    u32x4 o;
    o[0] = cvt_pk_bf16(a[0]*sc, a[1]*sc);
    o[1] = cvt_pk_bf16(a[2]*sc, a[3]*sc);
    o[2] = cvt_pk_bf16(b[0]*sc, b[1]*sc);
    o[3] = cvt_pk_bf16(b[2]*sc, b[3]*sc);
    *(u32x4*)((isH ? Hb : xs) + j*8) = o;
  }
}

__global__ __launch_bounds__(256) void scanC_k(const int* deg, const int* bsum,
                                               int* off, int* cursor, int n){
  __shared__ int ls[256];
  int b = blockIdx.x, t = threadIdx.x;
  int base = b*CHUNK + t*4;
  int v[4]; int s = 0;
  #pragma unroll
  for(int j = 0; j < 4; j++){ int i = base + j; v[j] = (i < n) ? deg[i]-1 : 0; s += v[j]; }
  ls[t] = s; __syncthreads();
  for(int d = 1; d < 256; d <<= 1){
    int tmp = (t >= d) ? ls[t-d] : 0;
    __syncthreads();
    ls[t] += tmp;
    __syncthreads();
  }
  int run = bsum[b] + ls[t] - s;   // exclusive prefix
  #pragma unroll
  for(int j = 0; j < 4; j++){
    int i = base + j;
    if(i < n){ off[i] = run; cursor[i] = run; run += v[j]; }
  }
}

__global__ void fill_k(const int* e32, const int* flag, int* cursor, int* srcs,
                       int e, int n){
  int i = blockIdx.x*256 + threadIdx.x;
  if(i >= e) return;
  int is32 = *flag;
  int r = eidx(e32, is32, i, n);
  int c = eidx(e32, is32, (long)e + i, n);
  int slot = atomicAdd(&cursor[c], 1);
  srcs[slot] = r;
}

// ---------------- fused GCN: CSR gather (bf16, pre-scaled) -> LDS -> GEMM ----------

__global__ __launch_bounds__(256) void gcn_k(const short* xs, const float* dinv,
    const int* offs, const int* deg, const int* srcs, const short* wt,
    const float* bias, short* hraw, float* sum, float* sumsq, int n){
  __shared__ char Alds[64*256];  // 64 rows x 128 bf16, XOR-swizzled
  const int t = threadIdx.x;
  const int row0 = blockIdx.x*64;
  const int g = t >> 4, lane16 = t & 15;
  for(int rr = 0; rr < 4; rr++){
    int row = g*4 + rr;
    int node = row0 + row;
    float acc[8] = {0,0,0,0,0,0,0,0};
    if(node < n){
      float di = dinv[node];
      bf16x8 sv = *(const bf16x8*)(xs + (long)node*DD + lane16*8);
      #pragma unroll
      for(int c = 0; c < 8; c++) acc[c] = bf2f(sv[c]);   // self: dinv[node]*x[node]
      int o0 = offs[node], cnt = deg[node] - 1;
      for(int jb = 0; jb < cnt; jb += 8){
        int rux[8]; float wk[8];
        #pragma unroll
        for(int k = 0; k < 8; k++){
          int jj = jb + k;
          bool ok = jj < cnt;
          rux[k] = srcs[o0 + (ok ? jj : cnt-1)];
          wk[k] = ok ? 1.f : 0.f;
        }
        #pragma unroll
        for(int k = 0; k < 8; k++){
          bf16x8 v = *(const bf16x8*)(xs + (long)rux[k]*DD + lane16*8);
          float wkk = wk[k];
          #pragma unroll
          for(int c = 0; c < 8; c++) acc[c] += bf2f(v[c])*wkk;
        }
      }
      #pragma unroll
      for(int c = 0; c < 8; c++) acc[c] *= di;
    }
    u32x4 o8;
    #pragma unroll
    for(int k = 0; k < 4; k++) o8[k] = cvt_pk_bf16(acc[2*k], acc[2*k+1]);
    int byte = row*256 + ((lane16*16) ^ ((row&7)<<4));
    *(u32x4*)(Alds + byte) = o8;
  }
  __syncthreads();
  const int w = t >> 6, ll = t & 63;
  const int lrow = ll & 15, lk = ll >> 4;
  f32x4 acc[4][2];
  #pragma unroll
  for(int m = 0; m < 4; m++) for(int j = 0; j < 2; j++) acc[m][j] = (f32x4){0,0,0,0};
  #pragma unroll
  for(int ks = 0; ks < 4; ks++){
    bf16x8 af[4];
    #pragma unroll
    for(int m = 0; m < 4; m++){
      int r = m*16 + lrow;
      int byte = r*256 + ((ks*64 + lk*16) ^ ((r&7)<<4));
      af[m] = *(const bf16x8*)(Alds + byte);
    }
    #pragma unroll
    for(int j = 0; j < 2; j++){
      int col = (w*2+j)*16 + lrow;
      bf16x8 bfr = *(const bf16x8*)(wt + col*128 + ks*32 + lk*8);
      #pragma unroll
      for(int m = 0; m < 4; m++)
        acc[m][j] = __builtin_amdgcn_mfma_f32_16x16x32_bf16(af[m], bfr, acc[m][j], 0,0,0);
    }
  }
  #pragma unroll
  for(int j = 0; j < 2; j++){
    int col = (w*2+j)*16 + lrow;
    float bv = bias[col];
    float s = 0.f, s2 = 0.f;
    #pragma unroll
    for(int m = 0; m < 4; m++){
      int rb = row0 + m*16 + lk*4;
      #pragma unroll
      for(int rr = 0; rr < 4; rr += 2){
        int rowA = rb + rr, rowB = rb + rr + 1;
        float hA = acc[m][j][rr] + bv;
        float hB = acc[m][j][rr+1] + bv;
        uint32_t u = cvt_pk_bf16(hA, hB);
        if(rowA < n){ hraw[(long)rowA*DD + col] = (short)(u & 0xffff); s += hA; s2 += hA*hA; }
        if(rowB < n){ hraw[(long)rowB*DD + col] = (short)(u >> 16);   s += hB; s2 += hB*hB; }
      }
    }
    s  += __shfl_xor(s, 16);  s  += __shfl_xor(s, 32);
    s2 += __shfl_xor(s2, 16); s2 += __shfl_xor(s2, 32);
    if(lk == 0){
      atomicAdd(&sum[col], s);
      atomicAdd(&sumsq[col], s2);
    }
  }
}

// ---------------- fused GRU: M=32, BN inline, RHl side-tile, LDS-resident H ----------
// Alds = [32][256] bf16 swizzled, [h_act | H]; H half never overwritten.
// RHl  = [32][128] bf16 swizzled, R*H. Zl = Z. 34 KB total -> 4 blocks/CU.

__global__ __launch_bounds__(256) void gru_k(const short* hraw, const short* Hb,
    const short* wtzr, const short* wth, const float* sum, const float* sumsq,
    const float* gamma, const float* beta, const float* prelu,
    const float* bz, const float* br, const float* bh, float* out, int n){
  __shared__ char Alds[32*512];
  __shared__ char RHl[32*256];
  __shared__ short Zl[32][132];
  __shared__ float sSc[128], sSh[128];
  const int t = threadIdx.x;
  const int row0 = blockIdx.x*32;
  const float pa = prelu[0];
  if(t < 128){
    float inv_n = 1.0f/(float)n;
    float mean = sum[t]*inv_n;
    float var = sumsq[t]*inv_n - mean*mean;
    float sc = gamma[t]*rsqrtf(var + 1e-5f);
    sSc[t] = sc; sSh[t] = beta[t] - mean*sc;
  }
  __syncthreads();
  // stage [h_act | H]
  for(int u = t; u < 1024; u += 256){
    int r = u >> 5, ku = u & 31;
    int grow = row0 + r;
    u32x4 o = {0,0,0,0};
    if(grow < n){
      if(ku < 16){
        bf16x8 hv = *(const bf16x8*)(hraw + (long)grow*DD + ku*8);
        float f[8];
        #pragma unroll
        for(int j = 0; j < 8; j++){
          int c = ku*8 + j;
          float v = bf2f(hv[j])*sSc[c] + sSh[c];
          f[j] = v > 0.f ? v : pa*v;
        }
        #pragma unroll
        for(int k = 0; k < 4; k++) o[k] = cvt_pk_bf16(f[2*k], f[2*k+1]);
      } else {
        o = *(const u32x4*)(Hb + (long)grow*DD + (ku-16)*8);
      }
    }
    int byte = r*512 + ((ku*16) ^ ((r&7)<<4));
    *(u32x4*)(Alds + byte) = o;
  }
  __syncthreads();
  const int w = t >> 6, l = t & 63;
  const int lrow = l & 15, lk = l >> 4;
  // ---- ZR GEMM: wave w -> cols [64w, 64w+64), B double-buffered ----
  f32x4 acc[2][4];
  #pragma unroll
  for(int m = 0; m < 2; m++) for(int j = 0; j < 4; j++) acc[m][j] = (f32x4){0,0,0,0};
  {
    const short* bbase = wtzr + (long)(w*64 + lrow)*256 + lk*8;
    bf16x8 bc[4], bn[4];
    #pragma unroll
    for(int j = 0; j < 4; j++) bc[j] = *(const bf16x8*)(bbase + j*16*256);
    #pragma unroll
    for(int ks = 0; ks < 8; ks++){
      if(ks < 7){
        #pragma unroll
        for(int j = 0; j < 4; j++) bn[j] = *(const bf16x8*)(bbase + j*16*256 + (ks+1)*32);
      }
      bf16x8 af[2];
      #pragma unroll
      for(int m = 0; m < 2; m++){
        int r = m*16 + lrow;
        int byte = r*512 + ((ks*64 + lk*16) ^ ((r&7)<<4));
        af[m] = *(const bf16x8*)(Alds + byte);
      }
      #pragma unroll
      for(int j = 0; j < 4; j++)
        #pragma unroll
        for(int m = 0; m < 2; m++)
          acc[m][j] = __builtin_amdgcn_mfma_f32_16x16x32_bf16(af[m], bc[j], acc[m][j], 0,0,0);
      if(ks < 7){
        #pragma unroll
        for(int j = 0; j < 4; j++) bc[j] = bn[j];
      }
    }
  }
  // ---- gates: Z -> Zl; R*H -> RHl (H read from Alds, which is never overwritten) ----
  #pragma unroll
  for(int j = 0; j < 4; j++){
    int col256 = w*64 + j*16 + lrow;
    if(col256 < 128){
      float bv = bz[col256];
      #pragma unroll
      for(int m = 0; m < 2; m++){
        #pragma unroll
        for(int rr = 0; rr < 4; rr += 2){
          int rowA = m*16 + lk*4 + rr;
          float zA = sigm(acc[m][j][rr] + bv);
          float zB = sigm(acc[m][j][rr+1] + bv);
          uint32_t u = cvt_pk_bf16(zA, zB);
          Zl[rowA][col256]   = (short)(u & 0xffff);
          Zl[rowA+1][col256] = (short)(u >> 16);
        }
      }
    } else {
      int col = col256 - 128;
      float bv = br[col];
      #pragma unroll
      for(int m = 0; m < 2; m++){
        #pragma unroll
        for(int rr = 0; rr < 4; rr += 2){
          int rowA = m*16 + lk*4 + rr, rowB = rowA + 1;
          int hbA = rowA*512 + ((2*col256) ^ ((rowA&7)<<4));
          int hbB = rowB*512 + ((2*col256) ^ ((rowB&7)<<4));
          float rhA = sigm(acc[m][j][rr] + bv)   * bf2f(*(const short*)(Alds + hbA));
          float rhB = sigm(acc[m][j][rr+1] + bv) * bf2f(*(const short*)(Alds + hbB));
          uint32_t u = cvt_pk_bf16(rhA, rhB);
          int obA = rowA*256 + ((2*col) ^ ((rowA&7)<<4));
          int obB = rowB*256 + ((2*col) ^ ((rowB&7)<<4));
          *(short*)(RHl + obA) = (short)(u & 0xffff);
          *(short*)(RHl + obB) = (short)(u >> 16);
        }
      }
    }
  }
  __syncthreads();
  // ---- HT GEMM: wave w -> cols [32w, 32w+32); K 0-127 from Alds(h), 128-255 from RHl ----
  f32x4 acc2[2][2];
  #pragma unroll
  for(int m = 0; m < 2; m++) for(int j = 0; j < 2; j++) acc2[m][j] = (f32x4){0,0,0,0};
  {
    const short* bbase = wth + (long)(w*32 + lrow)*256 + lk*8;
    bf16x8 bc[2], bn[2];
    #pragma unroll
    for(int j = 0; j < 2; j++) bc[j] = *(const bf16x8*)(bbase + j*16*256);
    #pragma unroll
    for(int ks = 0; ks < 8; ks++){
      if(ks < 7){
        #pragma unroll
        for(int j = 0; j < 2; j++) bn[j] = *(const bf16x8*)(bbase + j*16*256 + (ks+1)*32);
      }
      bf16x8 af[2];
      #pragma unroll
      for(int m = 0; m < 2; m++){
        int r = m*16 + lrow;
        int byte;
        if(ks < 4) byte = r*512 + ((ks*64 + lk*16) ^ ((r&7)<<4));
        else       byte = -1;
        bf16x8 v;
        if(ks < 4) v = *(const bf16x8*)(Alds + byte);
        else {
          int b2 = r*256 + (((ks-4)*64 + lk*16) ^ ((r&7)<<4));
          v = *(const bf16x8*)(RHl + b2);
        }
        af[m] = v;
      }
      #pragma unroll
      for(int j = 0; j < 2; j++)
        #pragma unroll
        for(int m = 0; m < 2; m++)
          acc2[m][j] = __builtin_amdgcn_mfma_f32_16x16x32_bf16(af[m], bc[j], acc2[m][j], 0,0,0);
      if(ks < 7){
        #pragma unroll
        for(int j = 0; j < 2; j++) bc[j] = bn[j];
      }
    }
  }
  // ---- epilogue: out = z*H + (1-z)*tanh(ht);  H and Z from LDS ----
  #pragma unroll
  for(int j = 0; j < 2; j++){
    int col = w*32 + j*16 + lrow;
    float bv = bh[col];
    #pragma unroll
    for(int m = 0; m < 2; m++){
      #pragma unroll
      for(int rr = 0; rr < 4; rr++){
        int row = m*16 + lk*4 + rr;
        int grow = row0 + row;
        if(grow < n){
          float ht = tanh_f(acc2[m][j][rr] + bv);
          float z = bf2f(Zl[row][col]);
          int hb = row*512 + ((2*(128+col)) ^ ((row&7)<<4));
          float Hv = bf2f(*(const short*)(Alds + hb));
          out[(long)grow*DD + col] = z*Hv + (1.f - z)*ht;
        }
      }
    }
  }
}

// ---------------- launch ----------------

extern "C" void kernel_launch(void* const* d_in, const int* in_sizes, int n_in,
                              void* d_out, int out_size, void* d_ws, size_t ws_size,
                              hipStream_t stream){
  const float* x     = (const float*)d_in[0];
  const int*   e32   = (const int*)d_in[1];
  const float* H     = (const float*)d_in[2];
  const float* Wg    = (const float*)d_in[3];
  const float* bg    = (const float*)d_in[4];
  const float* gamma = (const float*)d_in[5];
  const float* beta  = (const float*)d_in[6];
  const float* prelu = (const float*)d_in[7];
  const float* Wz    = (const float*)d_in[8];
  const float* bz    = (const float*)d_in[9];
  const float* Wr    = (const float*)d_in[10];
  const float* br    = (const float*)d_in[11];
  const float* Wh    = (const float*)d_in[12];
  const float* bh    = (const float*)d_in[13];
  float* out = (float*)d_out;
  const int n = in_sizes[0] / DD;
  const int e = in_sizes[1] / 2;
  const int nb = (n + CHUNK - 1) / CHUNK;

  char* ws = (char*)d_ws;
  size_t o = 0;
  auto alloc = [&](size_t bytes)->char*{
    char* p = ws + o; o = (o + bytes + 255) & ~(size_t)255; return p;
  };
  int*   deg    = (int*)  alloc(4L*n);
  float* dinv   = (float*)alloc(4L*n);
  int*   flag   = (int*)  alloc(256);   // flag+sum+sumsq contiguous: one memset
  float* sum    = (float*)alloc(512);
  float* sumsq  = (float*)alloc(512);
  int*   bsum   = (int*)  alloc(4L*nb);
  int*   offs   = (int*)  alloc(4L*n);
  int*   cursor = (int*)  alloc(4L*n);
  int*   srcs   = (int*)  alloc(4L*e);
  short* wtg    = (short*)alloc(128L*128*2);
  short* wtzr   = (short*)alloc(256L*256*2);
  short* wth    = (short*)alloc(128L*256*2);
  short* hraw   = (short*)alloc(2L*n*DD);
  short* xs     = (short*)alloc(2L*n*DD);
  short* Hb     = (short*)alloc(2L*n*DD);

  hipMemsetAsync(flag, 0, 1280, stream);   // flag + sum + sumsq

  int gi = (n + 255)/256;
  int ge = (e + 255)/256;
  int ginit = gi > ge ? gi : ge;
  if(ginit < 448) ginit = 448;             // cover 114688 weight elements
  init_k<<<ginit, 256, 0, stream>>>(deg, e32, flag, Wg, Wz, Wr, Wh, wtg, wtzr, wth, n, e);
  deg_k<<<ge, 256, 0, stream>>>(e32, flag, deg, e, n);
  dscanA_k<<<nb + gi, 256, 0, stream>>>(deg, bsum, dinv, n, nb);
  {
    int cvb = (int)((2L*n*(DD/8) + 255) / 256);
    scanBcvt_k<<<1 + cvb, 256, 0, stream>>>(bsum, nb, x, H, dinv, xs, Hb, n);
  }
  scanC_k<<<nb, 256, 0, stream>>>(deg, bsum, offs, cursor, n);
  fill_k<<<ge, 256, 0, stream>>>(e32, flag, cursor, srcs, e, n);
  gcn_k<<<(n + 63)/64, 256, 0, stream>>>(xs, dinv, offs, deg, srcs, wtg, bg, hraw, sum, sumsq, n);
  gru_k<<<(n + 31)/32, 256, 0, stream>>>(hraw, Hb, wtzr, wth, sum, sumsq, gamma, beta, prelu, bz, br, bh, out, n);
}

// Round 8
// 264.586 us; speedup vs baseline: 5.2385x; 1.0266x over previous
//
#include <hip/hip_runtime.h>
#include <hip/hip_bf16.h>
#include <stdint.h>

#define DD 128
#define CHUNK 1024

typedef short bf16x8 __attribute__((ext_vector_type(8)));
typedef short bf16x4 __attribute__((ext_vector_type(4)));
typedef float f32x4 __attribute__((ext_vector_type(4)));
typedef uint32_t u32x4 __attribute__((ext_vector_type(4)));

__device__ __forceinline__ short f2bf(float f){
  union { float f; uint32_t u; } v; v.f = f;
  uint32_t r = v.u + 0x7fffu + ((v.u >> 16) & 1u);
  return (short)(r >> 16);
}
__device__ __forceinline__ float bf2f(short s){
  union { uint32_t u; float f; } v; v.u = ((uint32_t)(uint16_t)s) << 16;
  return v.f;
}
// packed bf16 convert: lo = bf16(a), hi = bf16(b)  (RNE, hardware)
__device__ __forceinline__ uint32_t cvt_pk_bf16(float a, float b){
  uint32_t r;
  asm("v_cvt_pk_bf16_f32 %0, %1, %2" : "=v"(r) : "v"(a), "v"(b));
  return r;
}
__device__ __forceinline__ float sigm(float x){ return 1.0f/(1.0f + __expf(-x)); }
__device__ __forceinline__ float tanh_f(float x){ return 1.0f - 2.0f/(__expf(2.0f*x) + 1.0f); }

// ---------------- init: deg=1, edge-dtype detect, all weight transposes ----------------

__global__ __launch_bounds__(256) void init_k(int* deg, const int* e32, int* flag,
    const float* Wg, const float* Wz, const float* Wr, const float* Wh,
    short* wtg, short* wtzr, short* wth, int n, int e){
  int i = blockIdx.x*256 + threadIdx.x;
  if(i < n) deg[i] = 1;                       // self loop
  if(i < e && e32[2*i+1] != 0) *flag = 1;     // int32 storage detected (benign race)
  if(i < 16384){
    int nn = i >> 7, k = i & 127;
    wtg[i] = f2bf(Wg[k*128 + nn]);
  } else if(i < 49152){
    int j = i - 16384; int nn = j >> 8, k = j & 255;
    wtzr[nn*256 + k] = f2bf(Wz[k*128 + nn]);
  } else if(i < 81920){
    int j = i - 49152; int nn = j >> 8, k = j & 255;
    wtzr[(128+nn)*256 + k] = f2bf(Wr[k*128 + nn]);
  } else if(i < 114688){
    int j = i - 81920; int nn = j >> 8, k = j & 255;
    wth[nn*256 + k] = f2bf(Wh[k*128 + nn]);
  }
}

__device__ __forceinline__ int eidx(const int* e32, int is32, long pos, int n){
  int v = is32 ? e32[pos] : e32[2*pos];
  return v < 0 ? 0 : (v >= n ? n-1 : v);
}

__global__ void deg_k(const int* e32, const int* flag, int* deg, int e, int n){
  int i = blockIdx.x*256 + threadIdx.x;
  if(i >= e) return;
  int is32 = *flag;
  int c = eidx(e32, is32, (long)e + i, n);  // cols = targets
  atomicAdd(&deg[c], 1);
}

// ---------------- scanA (per-chunk sums) + dinv, merged ----------------

__global__ __launch_bounds__(256) void dscanA_k(const int* deg, int* bsum,
                                                float* dinv, int n, int nb){
  int t = threadIdx.x;
  if((int)blockIdx.x < nb){
    __shared__ int ls[256];
    int b = blockIdx.x;
    int base = b*CHUNK + t*4;
    int s = 0;
    #pragma unroll
    for(int j = 0; j < 4; j++){ int i = base + j; if(i < n) s += deg[i] - 1; }
    ls[t] = s; __syncthreads();
    for(int off = 128; off > 0; off >>= 1){
      if(t < off) ls[t] += ls[t+off];
      __syncthreads();
    }
    if(t == 0) bsum[b] = ls[0];
  } else {
    int i = (blockIdx.x - nb)*256 + t;
    if(i < n) dinv[i] = rsqrtf((float)deg[i]);
  }
}

// ---------------- scanB (parallel exclusive scan of bsum) + cvtxh, merged ----------

__global__ __launch_bounds__(256) void scanBcvt_k(int* bsum, int nb,
    const float* x, const float* H, const float* dinv, short* xs, short* Hb, int n){
  int t = threadIdx.x;
  if(blockIdx.x == 0){
    if(nb <= 256){
      __shared__ int ls[256];
      int v = (t < nb) ? bsum[t] : 0;
      ls[t] = v; __syncthreads();
      for(int d = 1; d < 256; d <<= 1){
        int tmp = (t >= d) ? ls[t-d] : 0;
        __syncthreads();
        ls[t] += tmp;
        __syncthreads();
      }
      if(t < nb) bsum[t] = ls[t] - v;   // exclusive
    } else if(t == 0){
      int acc = 0;
      for(int i = 0; i < nb; i++){ int v = bsum[i]; bsum[i] = acc; acc += v; }
    }
  } else {
    long i = (long)(blockIdx.x - 1)*256 + t;
    long tot = (long)n*(DD/8);
    if(i >= 2*tot) return;
    bool isH = i >= tot;
    long j = isH ? i - tot : i;
    const float* src = isH ? H : x;
    f32x4 a = *(const f32x4*)(src + j*8);
    f32x4 b = *(const f32x4*)(src + j*8 + 4);
    float sc = isH ? 1.f : dinv[(int)(j >> 4)];
    u32x4 o;
    o[0] = cvt_pk_bf16(a[0]*sc, a[1]*sc);
    o[1] = cvt_pk_bf16(a[2]*sc, a[3]*sc);
    o[2] = cvt_pk_bf16(b[0]*sc, b[1]*sc);
    o[3] = cvt_pk_bf16(b[2]*sc, b[3]*sc);
    *(u32x4*)((isH ? Hb : xs) + j*8) = o;
  }
}

__global__ __launch_bounds__(256) void scanC_k(const int* deg, const int* bsum,
                                               int* off, int* cursor, int n){
  __shared__ int ls[256];
  int b = blockIdx.x, t = threadIdx.x;
  int base = b*CHUNK + t*4;
  int v[4]; int s = 0;
  #pragma unroll
  for(int j = 0; j < 4; j++){ int i = base + j; v[j] = (i < n) ? deg[i]-1 : 0; s += v[j]; }
  ls[t] = s; __syncthreads();
  for(int d = 1; d < 256; d <<= 1){
    int tmp = (t >= d) ? ls[t-d] : 0;
    __syncthreads();
    ls[t] += tmp;
    __syncthreads();
  }
  int run = bsum[b] + ls[t] - s;   // exclusive prefix
  #pragma unroll
  for(int j = 0; j < 4; j++){
    int i = base + j;
    if(i < n){ off[i] = run; cursor[i] = run; run += v[j]; }
  }
}

__global__ void fill_k(const int* e32, const int* flag, int* cursor, int* srcs,
                       int e, int n){
  int i = blockIdx.x*256 + threadIdx.x;
  if(i >= e) return;
  int is32 = *flag;
  int r = eidx(e32, is32, i, n);
  int c = eidx(e32, is32, (long)e + i, n);
  int slot = atomicAdd(&cursor[c], 1);
  srcs[slot] = r;
}

// ---------------- fused GCN: CSR gather (bf16, pre-scaled) -> LDS -> GEMM ----------
// B fragments (8 x 16B) loaded at kernel entry; in flight during the gather.

__global__ __launch_bounds__(256) void gcn_k(const short* xs, const float* dinv,
    const int* offs, const int* deg, const int* srcs, const short* wt,
    const float* bias, short* hraw, float* sum, float* sumsq, int n){
  __shared__ char Alds[64*256];  // 64 rows x 128 bf16, XOR-swizzled
  const int t = threadIdx.x;
  const int row0 = blockIdx.x*64;
  const int w = t >> 6, ll = t & 63;
  const int lrow = ll & 15, lk = ll >> 4;
  // ---- preload all B fragments (independent of everything) ----
  bf16x8 Bg[2][4];
  #pragma unroll
  for(int j = 0; j < 2; j++){
    int col = (w*2+j)*16 + lrow;
    #pragma unroll
    for(int ks = 0; ks < 4; ks++)
      Bg[j][ks] = *(const bf16x8*)(wt + col*128 + ks*32 + lk*8);
  }
  // ---- gather ----
  const int g = t >> 4, lane16 = t & 15;
  for(int rr = 0; rr < 4; rr++){
    int row = g*4 + rr;
    int node = row0 + row;
    float acc[8] = {0,0,0,0,0,0,0,0};
    if(node < n){
      float di = dinv[node];
      bf16x8 sv = *(const bf16x8*)(xs + (long)node*DD + lane16*8);
      #pragma unroll
      for(int c = 0; c < 8; c++) acc[c] = bf2f(sv[c]);   // self: dinv[node]*x[node]
      int o0 = offs[node], cnt = deg[node] - 1;
      for(int jb = 0; jb < cnt; jb += 8){
        int rux[8]; float wk[8];
        #pragma unroll
        for(int k = 0; k < 8; k++){
          int jj = jb + k;
          bool ok = jj < cnt;
          rux[k] = srcs[o0 + (ok ? jj : cnt-1)];
          wk[k] = ok ? 1.f : 0.f;
        }
        #pragma unroll
        for(int k = 0; k < 8; k++){
          bf16x8 v = *(const bf16x8*)(xs + (long)rux[k]*DD + lane16*8);
          float wkk = wk[k];
          #pragma unroll
          for(int c = 0; c < 8; c++) acc[c] += bf2f(v[c])*wkk;
        }
      }
      #pragma unroll
      for(int c = 0; c < 8; c++) acc[c] *= di;
    }
    u32x4 o8;
    #pragma unroll
    for(int k = 0; k < 4; k++) o8[k] = cvt_pk_bf16(acc[2*k], acc[2*k+1]);
    int byte = row*256 + ((lane16*16) ^ ((row&7)<<4));
    *(u32x4*)(Alds + byte) = o8;
  }
  __syncthreads();
  // ---- GEMM ----
  f32x4 acc[4][2];
  #pragma unroll
  for(int m = 0; m < 4; m++) for(int j = 0; j < 2; j++) acc[m][j] = (f32x4){0,0,0,0};
  #pragma unroll
  for(int ks = 0; ks < 4; ks++){
    bf16x8 af[4];
    #pragma unroll
    for(int m = 0; m < 4; m++){
      int r = m*16 + lrow;
      int byte = r*256 + ((ks*64 + lk*16) ^ ((r&7)<<4));
      af[m] = *(const bf16x8*)(Alds + byte);
    }
    #pragma unroll
    for(int j = 0; j < 2; j++)
      #pragma unroll
      for(int m = 0; m < 4; m++)
        acc[m][j] = __builtin_amdgcn_mfma_f32_16x16x32_bf16(af[m], Bg[j][ks], acc[m][j], 0,0,0);
  }
  #pragma unroll
  for(int j = 0; j < 2; j++){
    int col = (w*2+j)*16 + lrow;
    float bv = bias[col];
    float s = 0.f, s2 = 0.f;
    #pragma unroll
    for(int m = 0; m < 4; m++){
      int rb = row0 + m*16 + lk*4;
      #pragma unroll
      for(int rr = 0; rr < 4; rr += 2){
        int rowA = rb + rr, rowB = rb + rr + 1;
        float hA = acc[m][j][rr] + bv;
        float hB = acc[m][j][rr+1] + bv;
        uint32_t u = cvt_pk_bf16(hA, hB);
        if(rowA < n){ hraw[(long)rowA*DD + col] = (short)(u & 0xffff); s += hA; s2 += hA*hA; }
        if(rowB < n){ hraw[(long)rowB*DD + col] = (short)(u >> 16);   s += hB; s2 += hB*hB; }
      }
    }
    s  += __shfl_xor(s, 16);  s  += __shfl_xor(s, 32);
    s2 += __shfl_xor(s2, 16); s2 += __shfl_xor(s2, 32);
    if(lk == 0){
      atomicAdd(&sum[col], s);
      atomicAdd(&sumsq[col], s2);
    }
  }
}

// ---------------- fused GRU: M=32, deep B prefetch, phase-overlapped ----------------
// ZR GEMM: wave w -> cols [64w,64w+64); 4 half-K passes, B prefetched 1 pass ahead.
// First ZR pass loads issued at kernel entry (hide under stage).
// HT first pass issued during gates phase.

__global__ __launch_bounds__(256) void gru_k(const short* hraw, const short* Hb,
    const short* wtzr, const short* wth, const float* sum, const float* sumsq,
    const float* gamma, const float* beta, const float* prelu,
    const float* bz, const float* br, const float* bh, float* out, int n){
  __shared__ char Alds[32*512];
  __shared__ char RHl[32*256];
  __shared__ short Zl[32][132];
  __shared__ float sSc[128], sSh[128];
  const int t = threadIdx.x;
  const int row0 = blockIdx.x*32;
  const float pa = prelu[0];
  const int w = t >> 6, l = t & 63;
  const int lrow = l & 15, lk = l >> 4;
  const short* bbZR = wtzr + (long)(w*64 + lrow)*256 + lk*8;
  const short* bbHT = wth + (long)(w*32 + lrow)*256 + lk*8;

  // ---- issue ZR pass-0 B loads (j 0-1, ks 0-3) — fly during stage ----
  bf16x8 cur[2][4], nxt[2][4];
  #pragma unroll
  for(int j = 0; j < 2; j++)
    #pragma unroll
    for(int ks = 0; ks < 4; ks++)
      cur[j][ks] = *(const bf16x8*)(bbZR + j*4096 + ks*32);

  // ---- issue stage loads (4 x 16B per thread) ----
  u32x4 sreg[4];
  #pragma unroll
  for(int i = 0; i < 4; i++){
    int u = t + i*256;
    int r = u >> 5, ku = u & 31;
    int grow = row0 + r;
    u32x4 o = {0,0,0,0};
    if(grow < n){
      if(ku < 16) o = *(const u32x4*)(hraw + (long)grow*DD + ku*8);
      else        o = *(const u32x4*)(Hb + (long)grow*DD + (ku-16)*8);
    }
    sreg[i] = o;
  }
  // BN coeffs while loads fly
  if(t < 128){
    float inv_n = 1.0f/(float)n;
    float mean = sum[t]*inv_n;
    float var = sumsq[t]*inv_n - mean*mean;
    float sc = gamma[t]*rsqrtf(var + 1e-5f);
    sSc[t] = sc; sSh[t] = beta[t] - mean*sc;
  }
  __syncthreads();
  // convert + write LDS
  #pragma unroll
  for(int i = 0; i < 4; i++){
    int u = t + i*256;
    int r = u >> 5, ku = u & 31;
    u32x4 o = sreg[i];
    if(ku < 16){
      float f[8];
      #pragma unroll
      for(int j = 0; j < 8; j++){
        int c = ku*8 + j;
        short hv = (short)((o[j>>1] >> ((j&1)*16)) & 0xffff);
        float v = bf2f(hv)*sSc[c] + sSh[c];
        f[j] = v > 0.f ? v : pa*v;
      }
      #pragma unroll
      for(int k2 = 0; k2 < 4; k2++) o[k2] = cvt_pk_bf16(f[2*k2], f[2*k2+1]);
    }
    int byte = r*512 + ((ku*16) ^ ((r&7)<<4));
    *(u32x4*)(Alds + byte) = o;
  }
  __syncthreads();

  // ---- ZR GEMM: 4 passes of (2 cols x 4 ks), B prefetched one pass ahead ----
  f32x4 acc[2][4];
  #pragma unroll
  for(int m = 0; m < 2; m++) for(int j = 0; j < 4; j++) acc[m][j] = (f32x4){0,0,0,0};
  #pragma unroll
  for(int p = 0; p < 4; p++){
    const int jh = p >> 1, kh = p & 1;
    if(p < 3){
      const int pn = p + 1, jn = pn >> 1, kn = pn & 1;
      #pragma unroll
      for(int j = 0; j < 2; j++)
        #pragma unroll
        for(int ks = 0; ks < 4; ks++)
          nxt[j][ks] = *(const bf16x8*)(bbZR + (jn*2+j)*4096 + (kn*4+ks)*32);
    }
    #pragma unroll
    for(int ks = 0; ks < 4; ks++){
      const int ksg = kh*4 + ks;
      bf16x8 af[2];
      #pragma unroll
      for(int m = 0; m < 2; m++){
        int r = m*16 + lrow;
        af[m] = *(const bf16x8*)(Alds + r*512 + ((ksg*64 + lk*16) ^ ((r&7)<<4)));
      }
      #pragma unroll
      for(int j = 0; j < 2; j++)
        #pragma unroll
        for(int m = 0; m < 2; m++)
          acc[m][jh*2+j] = __builtin_amdgcn_mfma_f32_16x16x32_bf16(af[m], cur[j][ks], acc[m][jh*2+j], 0,0,0);
    }
    if(p < 3){
      #pragma unroll
      for(int j = 0; j < 2; j++)
        #pragma unroll
        for(int ks = 0; ks < 4; ks++)
          cur[j][ks] = nxt[j][ks];
    }
  }

  // ---- issue HT pass-0 B loads (fly during gates) ----
  #pragma unroll
  for(int j = 0; j < 2; j++)
    #pragma unroll
    for(int ks = 0; ks < 4; ks++)
      cur[j][ks] = *(const bf16x8*)(bbHT + j*4096 + ks*32);

  // ---- gates: waves 0-1 -> Z, waves 2-3 -> R*H (H from Alds, intact) ----
  #pragma unroll
  for(int j = 0; j < 4; j++){
    int col256 = w*64 + j*16 + lrow;
    if(col256 < 128){
      float bv = bz[col256];
      #pragma unroll
      for(int m = 0; m < 2; m++){
        #pragma unroll
        for(int rr = 0; rr < 4; rr += 2){
          int rowA = m*16 + lk*4 + rr;
          float zA = sigm(acc[m][j][rr] + bv);
          float zB = sigm(acc[m][j][rr+1] + bv);
          uint32_t u = cvt_pk_bf16(zA, zB);
          Zl[rowA][col256]   = (short)(u & 0xffff);
          Zl[rowA+1][col256] = (short)(u >> 16);
        }
      }
    } else {
      int col = col256 - 128;
      float bv = br[col];
      #pragma unroll
      for(int m = 0; m < 2; m++){
        #pragma unroll
        for(int rr = 0; rr < 4; rr += 2){
          int rowA = m*16 + lk*4 + rr, rowB = rowA + 1;
          int hbA = rowA*512 + ((2*col256) ^ ((rowA&7)<<4));
          int hbB = rowB*512 + ((2*col256) ^ ((rowB&7)<<4));
          float rhA = sigm(acc[m][j][rr] + bv)   * bf2f(*(const short*)(Alds + hbA));
          float rhB = sigm(acc[m][j][rr+1] + bv) * bf2f(*(const short*)(Alds + hbB));
          uint32_t u = cvt_pk_bf16(rhA, rhB);
          int obA = rowA*256 + ((2*col) ^ ((rowA&7)<<4));
          int obB = rowB*256 + ((2*col) ^ ((rowB&7)<<4));
          *(short*)(RHl + obA) = (short)(u & 0xffff);
          *(short*)(RHl + obB) = (short)(u >> 16);
        }
      }
    }
  }
  __syncthreads();

  // ---- HT GEMM: 2 passes of (2 cols x 4 ks); K 0-127 Alds(h), 128-255 RHl ----
  f32x4 acc2[2][2];
  #pragma unroll
  for(int m = 0; m < 2; m++) for(int j = 0; j < 2; j++) acc2[m][j] = (f32x4){0,0,0,0};
  #pragma unroll
  for(int p = 0; p < 2; p++){
    if(p < 1){
      #pragma unroll
      for(int j = 0; j < 2; j++)
        #pragma unroll
        for(int ks = 0; ks < 4; ks++)
          nxt[j][ks] = *(const bf16x8*)(bbHT + j*4096 + (4+ks)*32);
    }
    #pragma unroll
    for(int ks = 0; ks < 4; ks++){
      const int ksg = p*4 + ks;
      bf16x8 af[2];
      #pragma unroll
      for(int m = 0; m < 2; m++){
        int r = m*16 + lrow;
        if(ksg < 4)
          af[m] = *(const bf16x8*)(Alds + r*512 + ((ksg*64 + lk*16) ^ ((r&7)<<4)));
        else
          af[m] = *(const bf16x8*)(RHl + r*256 + (((ksg-4)*64 + lk*16) ^ ((r&7)<<4)));
      }
      #pragma unroll
      for(int j = 0; j < 2; j++)
        #pragma unroll
        for(int m = 0; m < 2; m++)
          acc2[m][j] = __builtin_amdgcn_mfma_f32_16x16x32_bf16(af[m], cur[j][ks], acc2[m][j], 0,0,0);
    }
    if(p < 1){
      #pragma unroll
      for(int j = 0; j < 2; j++)
        #pragma unroll
        for(int ks = 0; ks < 4; ks++)
          cur[j][ks] = nxt[j][ks];
    }
  }

  // ---- epilogue: out = z*H + (1-z)*tanh(ht);  H and Z from LDS ----
  #pragma unroll
  for(int j = 0; j < 2; j++){
    int col = w*32 + j*16 + lrow;
    float bv = bh[col];
    #pragma unroll
    for(int m = 0; m < 2; m++){
      #pragma unroll
      for(int rr = 0; rr < 4; rr++){
        int row = m*16 + lk*4 + rr;
        int grow = row0 + row;
        if(grow < n){
          float ht = tanh_f(acc2[m][j][rr] + bv);
          float z = bf2f(Zl[row][col]);
          int hb = row*512 + ((2*(128+col)) ^ ((row&7)<<4));
          float Hv = bf2f(*(const short*)(Alds + hb));
          out[(long)grow*DD + col] = z*Hv + (1.f - z)*ht;
        }
      }
    }
  }
}

// ---------------- launch ----------------

extern "C" void kernel_launch(void* const* d_in, const int* in_sizes, int n_in,
                              void* d_out, int out_size, void* d_ws, size_t ws_size,
                              hipStream_t stream){
  const float* x     = (const float*)d_in[0];
  const int*   e32   = (const int*)d_in[1];
  const float* H     = (const float*)d_in[2];
  const float* Wg    = (const float*)d_in[3];
  const float* bg    = (const float*)d_in[4];
  const float* gamma = (const float*)d_in[5];
  const float* beta  = (const float*)d_in[6];
  const float* prelu = (const float*)d_in[7];
  const float* Wz    = (const float*)d_in[8];
  const float* bz    = (const float*)d_in[9];
  const float* Wr    = (const float*)d_in[10];
  const float* br    = (const float*)d_in[11];
  const float* Wh    = (const float*)d_in[12];
  const float* bh    = (const float*)d_in[13];
  float* out = (float*)d_out;
  const int n = in_sizes[0] / DD;
  const int e = in_sizes[1] / 2;
  const int nb = (n + CHUNK - 1) / CHUNK;

  char* ws = (char*)d_ws;
  size_t o = 0;
  auto alloc = [&](size_t bytes)->char*{
    char* p = ws + o; o = (o + bytes + 255) & ~(size_t)255; return p;
  };
  int*   deg    = (int*)  alloc(4L*n);
  float* dinv   = (float*)alloc(4L*n);
  int*   flag   = (int*)  alloc(256);   // flag+sum+sumsq contiguous: one memset
  float* sum    = (float*)alloc(512);
  float* sumsq  = (float*)alloc(512);
  int*   bsum   = (int*)  alloc(4L*nb);
  int*   offs   = (int*)  alloc(4L*n);
  int*   cursor = (int*)  alloc(4L*n);
  int*   srcs   = (int*)  alloc(4L*e);
  short* wtg    = (short*)alloc(128L*128*2);
  short* wtzr   = (short*)alloc(256L*256*2);
  short* wth    = (short*)alloc(128L*256*2);
  short* hraw   = (short*)alloc(2L*n*DD);
  short* xs     = (short*)alloc(2L*n*DD);
  short* Hb     = (short*)alloc(2L*n*DD);

  hipMemsetAsync(flag, 0, 1280, stream);   // flag + sum + sumsq

  int gi = (n + 255)/256;
  int ge = (e + 255)/256;
  int ginit = gi > ge ? gi : ge;
  if(ginit < 448) ginit = 448;             // cover 114688 weight elements
  init_k<<<ginit, 256, 0, stream>>>(deg, e32, flag, Wg, Wz, Wr, Wh, wtg, wtzr, wth, n, e);
  deg_k<<<ge, 256, 0, stream>>>(e32, flag, deg, e, n);
  dscanA_k<<<nb + gi, 256, 0, stream>>>(deg, bsum, dinv, n, nb);
  {
    int cvb = (int)((2L*n*(DD/8) + 255) / 256);
    scanBcvt_k<<<1 + cvb, 256, 0, stream>>>(bsum, nb, x, H, dinv, xs, Hb, n);
  }
  scanC_k<<<nb, 256, 0, stream>>>(deg, bsum, offs, cursor, n);
  fill_k<<<ge, 256, 0, stream>>>(e32, flag, cursor, srcs, e, n);
  gcn_k<<<(n + 63)/64, 256, 0, stream>>>(xs, dinv, offs, deg, srcs, wtg, bg, hraw, sum, sumsq, n);
  gru_k<<<(n + 31)/32, 256, 0, stream>>>(hraw, Hb, wtzr, wth, sum, sumsq, gamma, beta, prelu, bz, br, bh, out, n);
}